// Round 15
// baseline (1095.761 us; speedup 1.0000x reference)
//
#include <hip/hip_runtime.h>
#include <hip/hip_bf16.h>
#include <math.h>

// Fixed instance: B=1, Z=8, H=96, W=192, C=256
#define L_TOK   147456
#define CDIM    256
#define C3      768
#define HID     1024
#define NWIN    1024
#define NTOK    144
#define NHEADS  8
#define HD      32
#define SCALE   0.1767766952966369f   // 1/sqrt(32)

typedef __attribute__((ext_vector_type(8))) short bfrag;   // 8 bf16 (4 VGPRs)
typedef __attribute__((ext_vector_type(4))) float f32x4;

__device__ __forceinline__ ushort f2bf(float f) {
    __hip_bfloat16 h = __float2bfloat16(f);
    return *reinterpret_cast<ushort*>(&h);
}
__device__ __forceinline__ float bf2f(ushort u) {
    __hip_bfloat16 h = *reinterpret_cast<__hip_bfloat16*>(&u);
    return __bfloat162float(h);
}

// async global->LDS, 16B per lane; LDS dest = wave-uniform base + lane*16
__device__ __forceinline__ void gld16(const ushort* g, ushort* l) {
    __builtin_amdgcn_global_load_lds(
        (const __attribute__((address_space(1))) void*)g,
        (__attribute__((address_space(3))) void*)l, 16, 0, 0);
}

// window-order row gt -> spatial token index (shift + partition map; also the
// inverse scatter target for window-reverse + roll-back)
__device__ __forceinline__ int shift_src(int gt) {
    const int win = gt / NTOK;
    const int nt  = gt - win * NTOK;
    const int wz = win >> 8, wh = (win >> 4) & 15, ww = win & 15;
    const int lz = nt / 72;
    const int t2 = nt - lz * 72;
    const int lh = t2 / 12, lw = t2 - lh * 12;
    const int z = (wz * 2 + lz + 1) & 7;
    int h = wh * 6 + lh + 3;  if (h >= 96)  h -= 96;
    int w = ww * 12 + lw + 6; if (w >= 192) w -= 192;
    return (z * 96 + h) * 192 + w;
}

// ---------------------------------------------------------------------------
// LN1 + shift + window-partition gather -> bf16 rows. One wave per row.
// ---------------------------------------------------------------------------
__global__ __launch_bounds__(256) void ln1_kernel(const float* __restrict__ x,
                                                  const float* __restrict__ g,
                                                  const float* __restrict__ b,
                                                  ushort* __restrict__ xw,
                                                  int row0)
{
    const int wave = threadIdx.x >> 6;
    const int lane = threadIdx.x & 63;
    const int t = blockIdx.x * 4 + wave;
    const int src = shift_src(row0 + t);
    const float4 xv = *(const float4*)(x + (size_t)src * CDIM + lane * 4);
    float s  = xv.x + xv.y + xv.z + xv.w;
    float ss = xv.x*xv.x + xv.y*xv.y + xv.z*xv.z + xv.w*xv.w;
    #pragma unroll
    for (int off = 32; off; off >>= 1) {
        s  += __shfl_xor(s,  off);
        ss += __shfl_xor(ss, off);
    }
    const float mean = s * (1.0f / CDIM);
    const float var  = ss * (1.0f / CDIM) - mean * mean;
    const float rstd = rsqrtf(var + 1e-5f);
    const float4 gv = *(const float4*)(g + lane * 4);
    const float4 bv = *(const float4*)(b + lane * 4);
    union { ushort u[4]; uint2 q; } pk;
    pk.u[0] = f2bf((xv.x - mean) * rstd * gv.x + bv.x);
    pk.u[1] = f2bf((xv.y - mean) * rstd * gv.y + bv.y);
    pk.u[2] = f2bf((xv.z - mean) * rstd * gv.z + bv.z);
    pk.u[3] = f2bf((xv.w - mean) * rstd * gv.w + bv.w);
    *(uint2*)(xw + (size_t)t * CDIM + lane * 4) = pk.q;
}

// ---------------------------------------------------------------------------
// fp32 -> bf16 weight convert (n divisible by 1024)
// ---------------------------------------------------------------------------
__global__ __launch_bounds__(256) void cvt_kernel(const float* __restrict__ s,
                                                  ushort* __restrict__ d)
{
    const int i = (blockIdx.x * 256 + threadIdx.x) * 4;
    const float4 v = *(const float4*)(s + i);
    d[i + 0] = f2bf(v.x); d[i + 1] = f2bf(v.y);
    d[i + 2] = f2bf(v.z); d[i + 3] = f2bf(v.w);
}

// ---------------------------------------------------------------------------
// Combined bias+mask table, FP32, MFMA-fragment order:
//   comb[(((cls*8+h)*9+rb)*9+ct)*256 + lane*4 + reg]
// cls bits: (wz==3)<<2 | (wh==15)<<1 | (ww==15)
// ---------------------------------------------------------------------------
__global__ __launch_bounds__(256) void comb_pre_kernel(const float* __restrict__ bt,
                                                       const int* __restrict__ wti_p,
                                                       float* __restrict__ comb)
{
    const int e = blockIdx.x * 256 + threadIdx.x;   // < 8*8*81*256 = 1327104
    const int wti = *wti_p;
    const int reg  = e & 3;
    const int lane = (e >> 2) & 63;
    const int t    = e >> 8;
    const int ct = t % 9;
    const int rb = (t / 9) % 9;
    const int h  = (t / 81) % 8;
    const int cls = t / 648;
    const int i = rb * 16 + ((lane >> 4) << 2) + reg;
    const int j = ct * 16 + (lane & 15);
    const int zi = i / 72, ri = i - zi * 72, hi = ri / 12, wi = ri - (ri / 12) * 12;
    const int zj = j / 72, rj = j - zj * 72, hj = rj / 12, wj = rj - (rj / 12) * 12;
    const int idx = (zi + 2 * zj) * 828 + (hi + 6 * hj) * 23 + (wi - wj + 11);
    const float bias = bt[((size_t)idx * 64 + wti) * 8 + h];
    const int cz = (cls >> 2) & 1, ch = (cls >> 1) & 1, cw = cls & 1;
    const int ri_ = (cz ? (zi == 0 ? 1 : 2) : 0) * 9
                  + (ch ? (hi < 3 ? 1 : 2) : 0) * 3
                  + (cw ? (wi < 6 ? 1 : 2) : 0);
    const int rj_ = (cz ? (zj == 0 ? 1 : 2) : 0) * 9
                  + (ch ? (hj < 3 ? 1 : 2) : 0) * 3
                  + (cw ? (wj < 6 ? 1 : 2) : 0);
    comb[e] = bias + ((ri_ == rj_) ? 0.0f : -100.0f);
}

// ---------------------------------------------------------------------------
// MFMA attention: one wave per (local window, head). Q unscaled; SCALE applied
// in fp32 after QK^T (s = s*SCALE + bias).
// ---------------------------------------------------------------------------
__global__ __launch_bounds__(64) void attn_kernel(const ushort* __restrict__ qkv,
                                                  const float* __restrict__ comb,
                                                  ushort* __restrict__ outb,
                                                  int win0)
{
    __shared__ ushort vt[32][168];   // V^T, cols(j) padded: [144,160) zeroed
    __shared__ ushort pt[16][168];   // P tile, cols padded: [144,160) zeroed

    const int winl = blockIdx.x >> 3;
    const int head = blockIdx.x & 7;
    const int win  = win0 + winl;
    const int lane = threadIdx.x;
    const int g = lane >> 4, c = lane & 15;
    const int cls = (((win >> 8) == 3) ? 4 : 0)
                  | ((((win >> 4) & 15) == 15) ? 2 : 0)
                  | (((win & 15) == 15) ? 1 : 0);

    const ushort* qb = qkv + (((size_t)(winl * 3 + 0) * 8 + head) * NTOK) * HD;
    const ushort* kb = qkv + (((size_t)(winl * 3 + 1) * 8 + head) * NTOK) * HD;
    const ushort* vb = qkv + (((size_t)(winl * 3 + 2) * 8 + head) * NTOK) * HD;

    for (int i = lane; i < 512; i += 64) vt[i >> 4][144 + (i & 15)] = 0;
    for (int i = lane; i < 256; i += 64) pt[i >> 4][144 + (i & 15)] = 0;
    for (int base = lane * 8; base < NTOK * HD; base += 512) {
        const int j = base >> 5, d0 = base & 31;
        union { ushort u[8]; uint4 q; } tv;
        tv.q = *(const uint4*)(vb + base);
        #pragma unroll
        for (int e = 0; e < 8; ++e) vt[d0 + e][j] = tv.u[e];
    }
    __syncthreads();

    bfrag kf[9];
    #pragma unroll
    for (int ct = 0; ct < 9; ++ct)
        kf[ct] = *(const bfrag*)(kb + (size_t)(ct * 16 + c) * HD + g * 8);
    bfrag vf[2][5];
    #pragma unroll
    for (int nt = 0; nt < 2; ++nt)
        #pragma unroll
        for (int kt = 0; kt < 5; ++kt)
            vf[nt][kt] = *(const bfrag*)&vt[nt * 16 + c][kt * 32 + g * 8];

    const float* cb = comb + ((size_t)cls * 8 + head) * 81 * 256;

    for (int rb = 0; rb < 9; ++rb) {
        const bfrag aq = *(const bfrag*)(qb + (size_t)(rb * 16 + c) * HD + g * 8);
        f32x4 s[9];
        #pragma unroll
        for (int ct = 0; ct < 9; ++ct)
            s[ct] = __builtin_amdgcn_mfma_f32_16x16x32_bf16(
                aq, kf[ct], (f32x4){0.0f, 0.0f, 0.0f, 0.0f}, 0, 0, 0);

        // fp32 scale + bias + mask (fragment-ordered fp32 table, 16B/lane)
        #pragma unroll
        for (int ct = 0; ct < 9; ++ct) {
            const float4 bw = *(const float4*)(cb + (size_t)(rb * 9 + ct) * 256 + lane * 4);
            s[ct][0] = s[ct][0] * SCALE + bw.x;
            s[ct][1] = s[ct][1] * SCALE + bw.y;
            s[ct][2] = s[ct][2] * SCALE + bw.z;
            s[ct][3] = s[ct][3] * SCALE + bw.w;
        }

        float mx[4] = {-1e30f, -1e30f, -1e30f, -1e30f};
        #pragma unroll
        for (int ct = 0; ct < 9; ++ct)
            #pragma unroll
            for (int r = 0; r < 4; ++r) mx[r] = fmaxf(mx[r], s[ct][r]);
        #pragma unroll
        for (int off = 1; off < 16; off <<= 1)
            #pragma unroll
            for (int r = 0; r < 4; ++r) mx[r] = fmaxf(mx[r], __shfl_xor(mx[r], off));
        float sm[4] = {0.0f, 0.0f, 0.0f, 0.0f};
        #pragma unroll
        for (int ct = 0; ct < 9; ++ct)
            #pragma unroll
            for (int r = 0; r < 4; ++r) {
                const float e = __expf(s[ct][r] - mx[r]);
                s[ct][r] = e; sm[r] += e;
            }
        #pragma unroll
        for (int off = 1; off < 16; off <<= 1)
            #pragma unroll
            for (int r = 0; r < 4; ++r) sm[r] += __shfl_xor(sm[r], off);
        float inv[4];
        #pragma unroll
        for (int r = 0; r < 4; ++r) inv[r] = 1.0f / sm[r];

        #pragma unroll
        for (int ct = 0; ct < 9; ++ct)
            #pragma unroll
            for (int r = 0; r < 4; ++r)
                pt[g * 4 + r][ct * 16 + c] = f2bf(s[ct][r]);

        f32x4 o[2] = {(f32x4){0,0,0,0}, (f32x4){0,0,0,0}};
        #pragma unroll
        for (int kt = 0; kt < 5; ++kt) {
            const bfrag pa = *(const bfrag*)&pt[c][kt * 32 + g * 8];
            o[0] = __builtin_amdgcn_mfma_f32_16x16x32_bf16(pa, vf[0][kt], o[0], 0, 0, 0);
            o[1] = __builtin_amdgcn_mfma_f32_16x16x32_bf16(pa, vf[1][kt], o[1], 0, 0, 0);
        }

        const size_t ob = ((size_t)winl * NTOK + rb * 16 + g * 4) * CDIM + head * HD;
        #pragma unroll
        for (int nt = 0; nt < 2; ++nt)
            #pragma unroll
            for (int r = 0; r < 4; ++r)
                outb[ob + (size_t)r * CDIM + nt * 16 + c] = f2bf(o[nt][r] * inv[r]);
    }
}

// ---------------------------------------------------------------------------
// bf16 MFMA GEMM (phase-1): C = A(MxK) @ Bw(NxK)^T + bias. 128x128, BK=64.
// Grid: blockIdx.x = n-tile (fast), blockIdx.y = m-tile (A-panel L2-hot).
// EPI : 0 = QKV scatter (raw, no Q scale); 1 = proj+reverse+roll+residual
// ---------------------------------------------------------------------------
template<int EPI>
__global__ __launch_bounds__(256) void mgemm(const ushort* __restrict__ A,
                                             const ushort* __restrict__ Bw,
                                             const float* __restrict__ bias,
                                             void* __restrict__ outp,
                                             const float* __restrict__ resid,
                                             int K, int grow0)
{
    __shared__ __align__(16) ushort Asb[128 * 64];
    __shared__ __align__(16) ushort Bsb[128 * 64];

    const int tid = threadIdx.x;
    const int m0 = blockIdx.y * 128;
    const int n0 = blockIdx.x * 128;
    const int w = tid >> 6, lane = tid & 63;
    const int wm = w >> 1, wn = w & 1;
    const int fr = lane & 15, kg = lane >> 4;
    const int wbase = tid & 192;

    f32x4 acc[4][4];
    #pragma unroll
    for (int i = 0; i < 4; ++i)
        #pragma unroll
        for (int j = 0; j < 4; ++j)
            acc[i][j] = (f32x4){0.0f, 0.0f, 0.0f, 0.0f};

    int lrow[4], lsl[4];
    #pragma unroll
    for (int it = 0; it < 4; ++it) {
        const int s = it * 256 + tid;
        lrow[it] = s >> 3;
        lsl[it]  = ((s & 7) ^ (lrow[it] & 7)) * 8;
    }

    size_t aoff[4], boff[4];
    #pragma unroll
    for (int it = 0; it < 4; ++it) {
        aoff[it] = (size_t)(m0 + lrow[it]) * K;
        boff[it] = (size_t)(n0 + lrow[it]) * K;
    }

    for (int kt = 0; kt < K; kt += 64) {
        #pragma unroll
        for (int it = 0; it < 4; ++it)
            gld16(A + aoff[it] + kt + lsl[it], &Asb[(it * 256 + wbase) * 8]);
        #pragma unroll
        for (int it = 0; it < 4; ++it)
            gld16(Bw + boff[it] + kt + lsl[it], &Bsb[(it * 256 + wbase) * 8]);
        __syncthreads();

        #pragma unroll
        for (int kh = 0; kh < 2; ++kh) {
            bfrag af[4], bfv[4];
            #pragma unroll
            for (int fm = 0; fm < 4; ++fm) {
                const int r = wm * 64 + fm * 16 + fr;
                af[fm] = *(const bfrag*)&Asb[r * 64 + (((kh * 4 + kg) ^ (r & 7)) * 8)];
            }
            #pragma unroll
            for (int fn = 0; fn < 4; ++fn) {
                const int r = wn * 64 + fn * 16 + fr;
                bfv[fn] = *(const bfrag*)&Bsb[r * 64 + (((kh * 4 + kg) ^ (r & 7)) * 8)];
            }
            #pragma unroll
            for (int fm = 0; fm < 4; ++fm)
                #pragma unroll
                for (int fn = 0; fn < 4; ++fn)
                    acc[fm][fn] = __builtin_amdgcn_mfma_f32_16x16x32_bf16(
                        af[fm], bfv[fn], acc[fm][fn], 0, 0, 0);
        }
        __syncthreads();
    }

    #pragma unroll
    for (int fn = 0; fn < 4; ++fn) {
        const int col = n0 + wn * 64 + fn * 16 + fr;
        const float bv = bias[col];
        #pragma unroll
        for (int fm = 0; fm < 4; ++fm) {
            #pragma unroll
            for (int r = 0; r < 4; ++r) {
                const int mi = m0 + wm * 64 + fm * 16 + kg * 4 + r;
                float val = acc[fm][fn][r] + bv;
                if constexpr (EPI == 0) {
                    const int winl = mi / NTOK, nt = mi - (mi / NTOK) * NTOK;
                    const int sel = col >> 8, head = (col >> 5) & 7, d = col & 31;
                    ((ushort*)outp)[(((size_t)(winl * 3 + sel) * 8 + head) * NTOK + nt) * HD + d] = f2bf(val);
                } else {
                    const int p = shift_src(grow0 + mi);
                    ((float*)outp)[(size_t)p * CDIM + col] = resid[(size_t)p * CDIM + col] + val;
                }
            }
        }
    }
}

// ---------------------------------------------------------------------------
// Fused MLP v6: per block 32 rows of io. 256 thr (4 waves, pure n-split).
// B OPERANDS LOADED DIRECT GLOBAL->REGISTERS (weights are L2-resident; each
// lane's MFMA B-fragment is a contiguous aligned 16B; kg-lanes cover a 64B
// line). No SB, no staging barriers: only 2 barriers/strip (HS publish +
// HS reuse). LDS 24KB (XS 16KB + HS 8KB). Accumulation order identical to
// round-14 (kt,ks / kt2 sequences preserved) -> numerics unchanged.
// ---------------------------------------------------------------------------
__global__ __launch_bounds__(256) void mlp_fused(float* __restrict__ io,
                                                 const ushort* __restrict__ w1b,
                                                 const float* __restrict__ b1,
                                                 const ushort* __restrict__ w2b,
                                                 const float* __restrict__ b2,
                                                 const float* __restrict__ g2,
                                                 const float* __restrict__ beta2)
{
    __shared__ __align__(16) ushort lds[12288];   // 24KB
    ushort* XS = lds;            // 8192 ushorts: [32][256]
    ushort* HS = lds + 8192;     // 4096 ushorts: [32][128]

    const int tid = threadIdx.x;
    const int wn = tid >> 6, lane = tid & 63;
    const int fr = lane & 15, kg = lane >> 4;
    const int grow0 = blockIdx.x * 32;

    // ---- load x1 rows, LN2, pack bf16 -> XS (32 rows, 8 thr/row)
    {
        const int row = tid >> 3;
        const int oct = tid & 7;                 // 32 cols each
        const float* xr = io + (size_t)(grow0 + row) * CDIM + oct * 32;
        float4 v[8];
        float s = 0.0f, ss = 0.0f;
        #pragma unroll
        for (int j = 0; j < 8; ++j) {
            v[j] = *(const float4*)(xr + j * 4);
            s  += v[j].x + v[j].y + v[j].z + v[j].w;
            ss += v[j].x*v[j].x + v[j].y*v[j].y + v[j].z*v[j].z + v[j].w*v[j].w;
        }
        #pragma unroll
        for (int off = 1; off < 8; off <<= 1) {
            s  += __shfl_xor(s,  off);
            ss += __shfl_xor(ss, off);
        }
        const float mean = s * (1.0f / CDIM);
        const float var  = ss * (1.0f / CDIM) - mean * mean;
        const float rstd = rsqrtf(var + 1e-5f);
        #pragma unroll
        for (int j = 0; j < 4; ++j) {            // 4 slots of 8 elems
            const int c = oct * 32 + j * 8;
            const float4 ga = *(const float4*)(g2 + c);
            const float4 gb = *(const float4*)(g2 + c + 4);
            const float4 ba = *(const float4*)(beta2 + c);
            const float4 bb = *(const float4*)(beta2 + c + 4);
            union { ushort u[8]; uint4 q4; } pk;
            pk.u[0] = f2bf((v[2*j].x   - mean) * rstd * ga.x + ba.x);
            pk.u[1] = f2bf((v[2*j].y   - mean) * rstd * ga.y + ba.y);
            pk.u[2] = f2bf((v[2*j].z   - mean) * rstd * ga.z + ba.z);
            pk.u[3] = f2bf((v[2*j].w   - mean) * rstd * ga.w + ba.w);
            pk.u[4] = f2bf((v[2*j+1].x - mean) * rstd * gb.x + bb.x);
            pk.u[5] = f2bf((v[2*j+1].y - mean) * rstd * gb.y + bb.y);
            pk.u[6] = f2bf((v[2*j+1].z - mean) * rstd * gb.z + bb.z);
            pk.u[7] = f2bf((v[2*j+1].w - mean) * rstd * gb.w + bb.w);
            const int slot = oct * 4 + j;                 // 0..31
            *(uint4*)&XS[row * 256 + (slot ^ (row & 7)) * 8] = pk.q4;
        }
    }
    __syncthreads();                             // XS resident (read-only after)

    f32x4 acc[2][4];
    #pragma unroll
    for (int i = 0; i < 2; ++i)
        #pragma unroll
        for (int j = 0; j < 4; ++j)
            acc[i][j] = (f32x4){0.0f, 0.0f, 0.0f, 0.0f};

    for (int s = 0; s < 8; ++s) {                // hidden strips of 128
        // ---- GEMM1: C1(32x128) = X(32x256) @ W1s^T, B direct from global
        f32x4 c1[2][2];
        #pragma unroll
        for (int i = 0; i < 2; ++i) { c1[i][0] = (f32x4){0,0,0,0}; c1[i][1] = (f32x4){0,0,0,0}; }
        #pragma unroll
        for (int kt = 0; kt < 4; ++kt) {
            #pragma unroll
            for (int ks = 0; ks < 2; ++ks) {
                bfrag af[2], bw[2];
                #pragma unroll
                for (int fm = 0; fm < 2; ++fm) {
                    const int r = fm * 16 + fr;
                    const int slot = kt * 8 + ks * 4 + kg;
                    af[fm] = *(const bfrag*)&XS[r * 256 + (slot ^ (r & 7)) * 8];
                }
                #pragma unroll
                for (int fn = 0; fn < 2; ++fn) {
                    const int rc = wn * 32 + fn * 16 + fr;      // col in strip
                    bw[fn] = *(const bfrag*)(w1b + (size_t)(s * 128 + rc) * 256
                                             + kt * 64 + ks * 32 + kg * 8);
                }
                #pragma unroll
                for (int fm = 0; fm < 2; ++fm)
                    #pragma unroll
                    for (int fn = 0; fn < 2; ++fn)
                        c1[fm][fn] = __builtin_amdgcn_mfma_f32_16x16x32_bf16(
                            af[fm], bw[fn], c1[fm][fn], 0, 0, 0);
            }
        }

        if (s) __syncthreads();                  // prev strip's HS readers done

        // ---- +b1, GELU, plain writes to HS
        #pragma unroll
        for (int fn = 0; fn < 2; ++fn) {
            const int colh = wn * 32 + fn * 16 + fr;
            const float b1v = b1[s * 128 + colh];
            #pragma unroll
            for (int fm = 0; fm < 2; ++fm) {
                #pragma unroll
                for (int r = 0; r < 4; ++r) {
                    const int mi = fm * 16 + kg * 4 + r;
                    const float v = c1[fm][fn][r] + b1v;
                    const float ge = 0.5f * v * (1.0f + erff(v * 0.70710678118654752f));
                    HS[mi * 128 + ((colh >> 3) ^ (mi & 7)) * 8 + (colh & 7)] = f2bf(ge);
                }
            }
        }
        __syncthreads();                         // HS published

        // ---- GEMM2: acc(32x256) += h(32x128) @ W2s^T, B direct from global
        #pragma unroll
        for (int kt2 = 0; kt2 < 4; ++kt2) {
            bfrag af[2], bw[4];
            #pragma unroll
            for (int fm = 0; fm < 2; ++fm) {
                const int r = fm * 16 + fr;
                af[fm] = *(const bfrag*)&HS[r * 128 + (((kt2 * 4 + kg) ^ (r & 7)) * 8)];
            }
            #pragma unroll
            for (int fn = 0; fn < 4; ++fn) {
                const int rc = wn * 64 + fn * 16 + fr;          // output col
                bw[fn] = *(const bfrag*)(w2b + (size_t)rc * 1024
                                         + s * 128 + kt2 * 32 + kg * 8);
            }
            #pragma unroll
            for (int fm = 0; fm < 2; ++fm)
                #pragma unroll
                for (int fn = 0; fn < 4; ++fn)
                    acc[fm][fn] = __builtin_amdgcn_mfma_f32_16x16x32_bf16(
                        af[fm], bw[fn], acc[fm][fn], 0, 0, 0);
        }
    }

    // ---- epilogue: out = x1 + acc + b2
    #pragma unroll
    for (int fn = 0; fn < 4; ++fn) {
        const int col = wn * 64 + fn * 16 + fr;
        const float bv = b2[col];
        #pragma unroll
        for (int fm = 0; fm < 2; ++fm) {
            #pragma unroll
            for (int r = 0; r < 4; ++r) {
                const int mi = fm * 16 + kg * 4 + r;
                const size_t gi = (size_t)(grow0 + mi) * CDIM + col;
                io[gi] += acc[fm][fn][r] + bv;
            }
        }
    }
}

// ---------------------------------------------------------------------------
extern "C" void kernel_launch(void* const* d_in, const int* in_sizes, int n_in,
                              void* d_out, int out_size, void* d_ws, size_t ws_size,
                              hipStream_t stream)
{
    const float* x     = (const float*)d_in[0];
    const float* g1    = (const float*)d_in[1];
    const float* beta1 = (const float*)d_in[2];
    const float* wqkv  = (const float*)d_in[3];
    const float* bqkv  = (const float*)d_in[4];
    const float* btab  = (const float*)d_in[5];
    const float* wproj = (const float*)d_in[6];
    const float* bproj = (const float*)d_in[7];
    const float* g2    = (const float*)d_in[8];
    const float* beta2 = (const float*)d_in[9];
    const float* w1    = (const float*)d_in[10];
    const float* b1    = (const float*)d_in[11];
    const float* w2    = (const float*)d_in[12];
    const float* b2    = (const float*)d_in[13];
    const int*   wti   = (const int*)d_in[17];
    float* out = (float*)d_out;

    const size_t COMB_ELEMS = (size_t)8 * 8 * 81 * 256;                // 1327104
    const size_t WQKV_E = (size_t)C3 * CDIM, WP_E = (size_t)CDIM * CDIM;
    const size_t W1_E = (size_t)HID * CDIM,  W2_E = (size_t)CDIM * HID;
    const size_t base_bytes = COMB_ELEMS * 4
                            + (WQKV_E + WP_E + W1_E + W2_E) * 2;

    int nch = 32;
    for (int cand : {4, 8, 16, 32}) {
        const size_t rows = (size_t)L_TOK / cand;
        if (base_bytes + rows * (C3 + CDIM) * 2 <= ws_size) { nch = cand; break; }
    }
    const int wins_per = NWIN / nch;
    const int rows_per = wins_per * NTOK;

    char* wsp = (char*)d_ws;
    float* comb = (float*)wsp;   wsp += COMB_ELEMS * 4;
    ushort* wq_b = (ushort*)wsp; wsp += WQKV_E * 2;
    ushort* wp_b = (ushort*)wsp; wsp += WP_E * 2;
    ushort* w1_b = (ushort*)wsp; wsp += W1_E * 2;
    ushort* w2_b = (ushort*)wsp; wsp += W2_E * 2;
    ushort* ratt = (ushort*)wsp; wsp += (size_t)rows_per * CDIM * 2;  // xw/attn-out (shared)
    ushort* rbig = (ushort*)wsp;                 // rows_per * C3 bf16

    cvt_kernel<<<(int)(WQKV_E / 1024), 256, 0, stream>>>(wqkv, wq_b);
    cvt_kernel<<<(int)(WP_E   / 1024), 256, 0, stream>>>(wproj, wp_b);
    cvt_kernel<<<(int)(W1_E   / 1024), 256, 0, stream>>>(w1, w1_b);
    cvt_kernel<<<(int)(W2_E   / 1024), 256, 0, stream>>>(w2, w2_b);
    comb_pre_kernel<<<(int)(COMB_ELEMS / 256), 256, 0, stream>>>(btab, wti, comb);

    // Phase 1: LN1+shift (bf16, once) -> QKV -> attention -> proj(+reverse+roll+residual)
    for (int c = 0; c < nch; ++c) {
        const int row0 = c * rows_per;
        const int win0 = c * wins_per;
        ln1_kernel<<<rows_per / 4, 256, 0, stream>>>(x, g1, beta1, ratt, row0);
        mgemm<0><<<dim3(C3 / 128, rows_per / 128), 256, 0, stream>>>(
            ratt, wq_b, bqkv, rbig, nullptr, CDIM, row0);
        attn_kernel<<<wins_per * NHEADS, 64, 0, stream>>>(rbig, comb, ratt, win0);
        mgemm<1><<<dim3(CDIM / 128, rows_per / 128), 256, 0, stream>>>(
            ratt, wp_b, bproj, out, x, CDIM, row0);
    }

    // Phase 2: fused LN2 + MLP1 + GELU + MLP2 + residual (hidden stays on-chip)
    mlp_fused<<<L_TOK / 32, 256, 0, stream>>>(out, w1_b, b1, w2_b, b2, g2, beta2);
}

// Round 16
// 915.312 us; speedup vs baseline: 1.1971x; 1.1971x over previous
//
#include <hip/hip_runtime.h>
#include <hip/hip_bf16.h>
#include <math.h>

// Fixed instance: B=1, Z=8, H=96, W=192, C=256
#define L_TOK   147456
#define CDIM    256
#define C3      768
#define HID     1024
#define NWIN    1024
#define NTOK    144
#define NHEADS  8
#define HD      32
#define SCALE   0.1767766952966369f   // 1/sqrt(32)

typedef __attribute__((ext_vector_type(8))) short bfrag;   // 8 bf16 (4 VGPRs)
typedef __attribute__((ext_vector_type(4))) float f32x4;

__device__ __forceinline__ ushort f2bf(float f) {
    __hip_bfloat16 h = __float2bfloat16(f);
    return *reinterpret_cast<ushort*>(&h);
}
__device__ __forceinline__ float bf2f(ushort u) {
    __hip_bfloat16 h = *reinterpret_cast<__hip_bfloat16*>(&u);
    return __bfloat162float(h);
}

// async global->LDS, 16B per lane; LDS dest = wave-uniform base + lane*16
__device__ __forceinline__ void gld16(const ushort* g, ushort* l) {
    __builtin_amdgcn_global_load_lds(
        (const __attribute__((address_space(1))) void*)g,
        (__attribute__((address_space(3))) void*)l, 16, 0, 0);
}

// window-order row gt -> spatial token index (shift + partition map; also the
// inverse scatter target for window-reverse + roll-back)
__device__ __forceinline__ int shift_src(int gt) {
    const int win = gt / NTOK;
    const int nt  = gt - win * NTOK;
    const int wz = win >> 8, wh = (win >> 4) & 15, ww = win & 15;
    const int lz = nt / 72;
    const int t2 = nt - lz * 72;
    const int lh = t2 / 12, lw = t2 - lh * 12;
    const int z = (wz * 2 + lz + 1) & 7;
    int h = wh * 6 + lh + 3;  if (h >= 96)  h -= 96;
    int w = ww * 12 + lw + 6; if (w >= 192) w -= 192;
    return (z * 96 + h) * 192 + w;
}

// ---------------------------------------------------------------------------
// LN1 + shift + window-partition gather -> bf16 rows. One wave per row.
// ---------------------------------------------------------------------------
__global__ __launch_bounds__(256) void ln1_kernel(const float* __restrict__ x,
                                                  const float* __restrict__ g,
                                                  const float* __restrict__ b,
                                                  ushort* __restrict__ xw,
                                                  int row0)
{
    const int wave = threadIdx.x >> 6;
    const int lane = threadIdx.x & 63;
    const int t = blockIdx.x * 4 + wave;
    const int src = shift_src(row0 + t);
    const float4 xv = *(const float4*)(x + (size_t)src * CDIM + lane * 4);
    float s  = xv.x + xv.y + xv.z + xv.w;
    float ss = xv.x*xv.x + xv.y*xv.y + xv.z*xv.z + xv.w*xv.w;
    #pragma unroll
    for (int off = 32; off; off >>= 1) {
        s  += __shfl_xor(s,  off);
        ss += __shfl_xor(ss, off);
    }
    const float mean = s * (1.0f / CDIM);
    const float var  = ss * (1.0f / CDIM) - mean * mean;
    const float rstd = rsqrtf(var + 1e-5f);
    const float4 gv = *(const float4*)(g + lane * 4);
    const float4 bv = *(const float4*)(b + lane * 4);
    union { ushort u[4]; uint2 q; } pk;
    pk.u[0] = f2bf((xv.x - mean) * rstd * gv.x + bv.x);
    pk.u[1] = f2bf((xv.y - mean) * rstd * gv.y + bv.y);
    pk.u[2] = f2bf((xv.z - mean) * rstd * gv.z + bv.z);
    pk.u[3] = f2bf((xv.w - mean) * rstd * gv.w + bv.w);
    *(uint2*)(xw + (size_t)t * CDIM + lane * 4) = pk.q;
}

// ---------------------------------------------------------------------------
// fp32 -> bf16 weight convert (n divisible by 1024)
// ---------------------------------------------------------------------------
__global__ __launch_bounds__(256) void cvt_kernel(const float* __restrict__ s,
                                                  ushort* __restrict__ d)
{
    const int i = (blockIdx.x * 256 + threadIdx.x) * 4;
    const float4 v = *(const float4*)(s + i);
    d[i + 0] = f2bf(v.x); d[i + 1] = f2bf(v.y);
    d[i + 2] = f2bf(v.z); d[i + 3] = f2bf(v.w);
}

// ---------------------------------------------------------------------------
// Combined bias+mask table, FP32, MFMA-fragment order:
//   comb[(((cls*8+h)*9+rb)*9+ct)*256 + lane*4 + reg]
// cls bits: (wz==3)<<2 | (wh==15)<<1 | (ww==15)
// ---------------------------------------------------------------------------
__global__ __launch_bounds__(256) void comb_pre_kernel(const float* __restrict__ bt,
                                                       const int* __restrict__ wti_p,
                                                       float* __restrict__ comb)
{
    const int e = blockIdx.x * 256 + threadIdx.x;   // < 8*8*81*256 = 1327104
    const int wti = *wti_p;
    const int reg  = e & 3;
    const int lane = (e >> 2) & 63;
    const int t    = e >> 8;
    const int ct = t % 9;
    const int rb = (t / 9) % 9;
    const int h  = (t / 81) % 8;
    const int cls = t / 648;
    const int i = rb * 16 + ((lane >> 4) << 2) + reg;
    const int j = ct * 16 + (lane & 15);
    const int zi = i / 72, ri = i - zi * 72, hi = ri / 12, wi = ri - (ri / 12) * 12;
    const int zj = j / 72, rj = j - zj * 72, hj = rj / 12, wj = rj - (rj / 12) * 12;
    const int idx = (zi + 2 * zj) * 828 + (hi + 6 * hj) * 23 + (wi - wj + 11);
    const float bias = bt[((size_t)idx * 64 + wti) * 8 + h];
    const int cz = (cls >> 2) & 1, ch = (cls >> 1) & 1, cw = cls & 1;
    const int ri_ = (cz ? (zi == 0 ? 1 : 2) : 0) * 9
                  + (ch ? (hi < 3 ? 1 : 2) : 0) * 3
                  + (cw ? (wi < 6 ? 1 : 2) : 0);
    const int rj_ = (cz ? (zj == 0 ? 1 : 2) : 0) * 9
                  + (ch ? (hj < 3 ? 1 : 2) : 0) * 3
                  + (cw ? (wj < 6 ? 1 : 2) : 0);
    comb[e] = bias + ((ri_ == rj_) ? 0.0f : -100.0f);
}

// ---------------------------------------------------------------------------
// MFMA attention: one wave per (local window, head). Q unscaled; SCALE applied
// in fp32 after QK^T (s = s*SCALE + bias).
// ---------------------------------------------------------------------------
__global__ __launch_bounds__(64) void attn_kernel(const ushort* __restrict__ qkv,
                                                  const float* __restrict__ comb,
                                                  ushort* __restrict__ outb,
                                                  int win0)
{
    __shared__ ushort vt[32][168];   // V^T, cols(j) padded: [144,160) zeroed
    __shared__ ushort pt[16][168];   // P tile, cols padded: [144,160) zeroed

    const int winl = blockIdx.x >> 3;
    const int head = blockIdx.x & 7;
    const int win  = win0 + winl;
    const int lane = threadIdx.x;
    const int g = lane >> 4, c = lane & 15;
    const int cls = (((win >> 8) == 3) ? 4 : 0)
                  | ((((win >> 4) & 15) == 15) ? 2 : 0)
                  | (((win & 15) == 15) ? 1 : 0);

    const ushort* qb = qkv + (((size_t)(winl * 3 + 0) * 8 + head) * NTOK) * HD;
    const ushort* kb = qkv + (((size_t)(winl * 3 + 1) * 8 + head) * NTOK) * HD;
    const ushort* vb = qkv + (((size_t)(winl * 3 + 2) * 8 + head) * NTOK) * HD;

    for (int i = lane; i < 512; i += 64) vt[i >> 4][144 + (i & 15)] = 0;
    for (int i = lane; i < 256; i += 64) pt[i >> 4][144 + (i & 15)] = 0;
    for (int base = lane * 8; base < NTOK * HD; base += 512) {
        const int j = base >> 5, d0 = base & 31;
        union { ushort u[8]; uint4 q; } tv;
        tv.q = *(const uint4*)(vb + base);
        #pragma unroll
        for (int e = 0; e < 8; ++e) vt[d0 + e][j] = tv.u[e];
    }
    __syncthreads();

    bfrag kf[9];
    #pragma unroll
    for (int ct = 0; ct < 9; ++ct)
        kf[ct] = *(const bfrag*)(kb + (size_t)(ct * 16 + c) * HD + g * 8);
    bfrag vf[2][5];
    #pragma unroll
    for (int nt = 0; nt < 2; ++nt)
        #pragma unroll
        for (int kt = 0; kt < 5; ++kt)
            vf[nt][kt] = *(const bfrag*)&vt[nt * 16 + c][kt * 32 + g * 8];

    const float* cb = comb + ((size_t)cls * 8 + head) * 81 * 256;

    for (int rb = 0; rb < 9; ++rb) {
        const bfrag aq = *(const bfrag*)(qb + (size_t)(rb * 16 + c) * HD + g * 8);
        f32x4 s[9];
        #pragma unroll
        for (int ct = 0; ct < 9; ++ct)
            s[ct] = __builtin_amdgcn_mfma_f32_16x16x32_bf16(
                aq, kf[ct], (f32x4){0.0f, 0.0f, 0.0f, 0.0f}, 0, 0, 0);

        // fp32 scale + bias + mask (fragment-ordered fp32 table, 16B/lane)
        #pragma unroll
        for (int ct = 0; ct < 9; ++ct) {
            const float4 bw = *(const float4*)(cb + (size_t)(rb * 9 + ct) * 256 + lane * 4);
            s[ct][0] = s[ct][0] * SCALE + bw.x;
            s[ct][1] = s[ct][1] * SCALE + bw.y;
            s[ct][2] = s[ct][2] * SCALE + bw.z;
            s[ct][3] = s[ct][3] * SCALE + bw.w;
        }

        float mx[4] = {-1e30f, -1e30f, -1e30f, -1e30f};
        #pragma unroll
        for (int ct = 0; ct < 9; ++ct)
            #pragma unroll
            for (int r = 0; r < 4; ++r) mx[r] = fmaxf(mx[r], s[ct][r]);
        #pragma unroll
        for (int off = 1; off < 16; off <<= 1)
            #pragma unroll
            for (int r = 0; r < 4; ++r) mx[r] = fmaxf(mx[r], __shfl_xor(mx[r], off));
        float sm[4] = {0.0f, 0.0f, 0.0f, 0.0f};
        #pragma unroll
        for (int ct = 0; ct < 9; ++ct)
            #pragma unroll
            for (int r = 0; r < 4; ++r) {
                const float e = __expf(s[ct][r] - mx[r]);
                s[ct][r] = e; sm[r] += e;
            }
        #pragma unroll
        for (int off = 1; off < 16; off <<= 1)
            #pragma unroll
            for (int r = 0; r < 4; ++r) sm[r] += __shfl_xor(sm[r], off);
        float inv[4];
        #pragma unroll
        for (int r = 0; r < 4; ++r) inv[r] = 1.0f / sm[r];

        #pragma unroll
        for (int ct = 0; ct < 9; ++ct)
            #pragma unroll
            for (int r = 0; r < 4; ++r)
                pt[g * 4 + r][ct * 16 + c] = f2bf(s[ct][r]);

        f32x4 o[2] = {(f32x4){0,0,0,0}, (f32x4){0,0,0,0}};
        #pragma unroll
        for (int kt = 0; kt < 5; ++kt) {
            const bfrag pa = *(const bfrag*)&pt[c][kt * 32 + g * 8];
            o[0] = __builtin_amdgcn_mfma_f32_16x16x32_bf16(pa, vf[0][kt], o[0], 0, 0, 0);
            o[1] = __builtin_amdgcn_mfma_f32_16x16x32_bf16(pa, vf[1][kt], o[1], 0, 0, 0);
        }

        const size_t ob = ((size_t)winl * NTOK + rb * 16 + g * 4) * CDIM + head * HD;
        #pragma unroll
        for (int nt = 0; nt < 2; ++nt)
            #pragma unroll
            for (int r = 0; r < 4; ++r)
                outb[ob + (size_t)r * CDIM + nt * 16 + c] = f2bf(o[nt][r] * inv[r]);
    }
}

// ---------------------------------------------------------------------------
// bf16 MFMA GEMM (phase-1): C = A(MxK) @ Bw(NxK)^T + bias. 128x128, BK=64.
// Grid: blockIdx.x = n-tile (fast), blockIdx.y = m-tile (A-panel L2-hot).
// EPI : 0 = QKV scatter (raw, no Q scale); 1 = proj+reverse+roll+residual
// ---------------------------------------------------------------------------
template<int EPI>
__global__ __launch_bounds__(256) void mgemm(const ushort* __restrict__ A,
                                             const ushort* __restrict__ Bw,
                                             const float* __restrict__ bias,
                                             void* __restrict__ outp,
                                             const float* __restrict__ resid,
                                             int K, int grow0)
{
    __shared__ __align__(16) ushort Asb[128 * 64];
    __shared__ __align__(16) ushort Bsb[128 * 64];

    const int tid = threadIdx.x;
    const int m0 = blockIdx.y * 128;
    const int n0 = blockIdx.x * 128;
    const int w = tid >> 6, lane = tid & 63;
    const int wm = w >> 1, wn = w & 1;
    const int fr = lane & 15, kg = lane >> 4;
    const int wbase = tid & 192;

    f32x4 acc[4][4];
    #pragma unroll
    for (int i = 0; i < 4; ++i)
        #pragma unroll
        for (int j = 0; j < 4; ++j)
            acc[i][j] = (f32x4){0.0f, 0.0f, 0.0f, 0.0f};

    int lrow[4], lsl[4];
    #pragma unroll
    for (int it = 0; it < 4; ++it) {
        const int s = it * 256 + tid;
        lrow[it] = s >> 3;
        lsl[it]  = ((s & 7) ^ (lrow[it] & 7)) * 8;
    }

    size_t aoff[4], boff[4];
    #pragma unroll
    for (int it = 0; it < 4; ++it) {
        aoff[it] = (size_t)(m0 + lrow[it]) * K;
        boff[it] = (size_t)(n0 + lrow[it]) * K;
    }

    for (int kt = 0; kt < K; kt += 64) {
        #pragma unroll
        for (int it = 0; it < 4; ++it)
            gld16(A + aoff[it] + kt + lsl[it], &Asb[(it * 256 + wbase) * 8]);
        #pragma unroll
        for (int it = 0; it < 4; ++it)
            gld16(Bw + boff[it] + kt + lsl[it], &Bsb[(it * 256 + wbase) * 8]);
        __syncthreads();

        #pragma unroll
        for (int kh = 0; kh < 2; ++kh) {
            bfrag af[4], bfv[4];
            #pragma unroll
            for (int fm = 0; fm < 4; ++fm) {
                const int r = wm * 64 + fm * 16 + fr;
                af[fm] = *(const bfrag*)&Asb[r * 64 + (((kh * 4 + kg) ^ (r & 7)) * 8)];
            }
            #pragma unroll
            for (int fn = 0; fn < 4; ++fn) {
                const int r = wn * 64 + fn * 16 + fr;
                bfv[fn] = *(const bfrag*)&Bsb[r * 64 + (((kh * 4 + kg) ^ (r & 7)) * 8)];
            }
            #pragma unroll
            for (int fm = 0; fm < 4; ++fm)
                #pragma unroll
                for (int fn = 0; fn < 4; ++fn)
                    acc[fm][fn] = __builtin_amdgcn_mfma_f32_16x16x32_bf16(
                        af[fm], bfv[fn], acc[fm][fn], 0, 0, 0);
        }
        __syncthreads();
    }

    #pragma unroll
    for (int fn = 0; fn < 4; ++fn) {
        const int col = n0 + wn * 64 + fn * 16 + fr;
        const float bv = bias[col];
        #pragma unroll
        for (int fm = 0; fm < 4; ++fm) {
            #pragma unroll
            for (int r = 0; r < 4; ++r) {
                const int mi = m0 + wm * 64 + fm * 16 + kg * 4 + r;
                float val = acc[fm][fn][r] + bv;
                if constexpr (EPI == 0) {
                    const int winl = mi / NTOK, nt = mi - (mi / NTOK) * NTOK;
                    const int sel = col >> 8, head = (col >> 5) & 7, d = col & 31;
                    ((ushort*)outp)[(((size_t)(winl * 3 + sel) * 8 + head) * NTOK + nt) * HD + d] = f2bf(val);
                } else {
                    const int p = shift_src(grow0 + mi);
                    ((float*)outp)[(size_t)p * CDIM + col] = resid[(size_t)p * CDIM + col] + val;
                }
            }
        }
    }
}

// ---------------------------------------------------------------------------
// Fused MLP (round-14 passing structure; GELU switched to tanh-approx via
// hardware exp — |err| <= 3e-4 in h, negligible through W2): per block 32
// rows of io. 256 thr (4 waves). LDS 40KB:
//   XS [32][256] 16KB | HS [32][128] 8KB | SB 16KB staging
// ---------------------------------------------------------------------------
__global__ __launch_bounds__(256) void mlp_fused(float* __restrict__ io,
                                                 const ushort* __restrict__ w1b,
                                                 const float* __restrict__ b1,
                                                 const ushort* __restrict__ w2b,
                                                 const float* __restrict__ b2,
                                                 const float* __restrict__ g2,
                                                 const float* __restrict__ beta2)
{
    __shared__ __align__(16) ushort lds[20480];   // 40KB
    ushort* XS = lds;            // 8192 ushorts: [32][256]
    ushort* HS = lds + 8192;     // 4096 ushorts: [32][128]
    ushort* SB = lds + 12288;    // 8192 ushorts: staging (16KB)

    const int tid = threadIdx.x;
    const int wn = tid >> 6, lane = tid & 63;
    const int fr = lane & 15, kg = lane >> 4;
    const int wbase = tid & 192;                 // wn*64, wave-uniform
    const int grow0 = blockIdx.x * 32;

    // ---- load x1 rows, LN2, pack bf16 -> XS (32 rows, 8 thr/row)
    {
        const int row = tid >> 3;
        const int oct = tid & 7;                 // 32 cols each
        const float* xr = io + (size_t)(grow0 + row) * CDIM + oct * 32;
        float4 v[8];
        float s = 0.0f, ss = 0.0f;
        #pragma unroll
        for (int j = 0; j < 8; ++j) {
            v[j] = *(const float4*)(xr + j * 4);
            s  += v[j].x + v[j].y + v[j].z + v[j].w;
            ss += v[j].x*v[j].x + v[j].y*v[j].y + v[j].z*v[j].z + v[j].w*v[j].w;
        }
        #pragma unroll
        for (int off = 1; off < 8; off <<= 1) {
            s  += __shfl_xor(s,  off);
            ss += __shfl_xor(ss, off);
        }
        const float mean = s * (1.0f / CDIM);
        const float var  = ss * (1.0f / CDIM) - mean * mean;
        const float rstd = rsqrtf(var + 1e-5f);
        #pragma unroll
        for (int j = 0; j < 4; ++j) {            // 4 slots of 8 elems
            const int c = oct * 32 + j * 8;
            const float4 ga = *(const float4*)(g2 + c);
            const float4 gb = *(const float4*)(g2 + c + 4);
            const float4 ba = *(const float4*)(beta2 + c);
            const float4 bb = *(const float4*)(beta2 + c + 4);
            union { ushort u[8]; uint4 q4; } pk;
            pk.u[0] = f2bf((v[2*j].x   - mean) * rstd * ga.x + ba.x);
            pk.u[1] = f2bf((v[2*j].y   - mean) * rstd * ga.y + ba.y);
            pk.u[2] = f2bf((v[2*j].z   - mean) * rstd * ga.z + ba.z);
            pk.u[3] = f2bf((v[2*j].w   - mean) * rstd * ga.w + ba.w);
            pk.u[4] = f2bf((v[2*j+1].x - mean) * rstd * gb.x + bb.x);
            pk.u[5] = f2bf((v[2*j+1].y - mean) * rstd * gb.y + bb.y);
            pk.u[6] = f2bf((v[2*j+1].z - mean) * rstd * gb.z + bb.z);
            pk.u[7] = f2bf((v[2*j+1].w - mean) * rstd * gb.w + bb.w);
            const int slot = oct * 4 + j;                 // 0..31
            *(uint4*)&XS[row * 256 + (slot ^ (row & 7)) * 8] = pk.q4;
        }
    }

    f32x4 acc[2][4];
    #pragma unroll
    for (int i = 0; i < 2; ++i)
        #pragma unroll
        for (int j = 0; j < 4; ++j)
            acc[i][j] = (f32x4){0.0f, 0.0f, 0.0f, 0.0f};

    for (int s = 0; s < 8; ++s) {                // hidden strips of 128
        // ---- GEMM1: C1(32x128) = X(32x256) @ W1s^T
        f32x4 c1[2][2];
        #pragma unroll
        for (int i = 0; i < 2; ++i) { c1[i][0] = (f32x4){0,0,0,0}; c1[i][1] = (f32x4){0,0,0,0}; }
        for (int kt = 0; kt < 4; ++kt) {         // BK=64 over K=256
            __syncthreads();                     // SB free (prev readers done)
            #pragma unroll
            for (int i = 0; i < 4; ++i) {        // stage B1 [128][64] = 16KB
                const int L = i * 256 + tid;     // 1024 slots of 16B
                const int row = L >> 3;
                const int sl = (L & 7) ^ (row & 7);
                gld16(w1b + (size_t)(s * 128 + row) * 256 + kt * 64 + sl * 8,
                      &SB[(i * 256 + wbase) * 8]);
            }
            __syncthreads();                     // loads drained + visible
            #pragma unroll
            for (int ks = 0; ks < 2; ++ks) {
                bfrag af[2], bw[2];
                #pragma unroll
                for (int fm = 0; fm < 2; ++fm) {
                    const int r = fm * 16 + fr;
                    const int slot = kt * 8 + ks * 4 + kg;
                    af[fm] = *(const bfrag*)&XS[r * 256 + (slot ^ (r & 7)) * 8];
                }
                #pragma unroll
                for (int fn = 0; fn < 2; ++fn) {
                    const int r = wn * 32 + fn * 16 + fr;
                    const int slot = ks * 4 + kg;
                    bw[fn] = *(const bfrag*)&SB[r * 64 + (slot ^ (r & 7)) * 8];
                }
                #pragma unroll
                for (int fm = 0; fm < 2; ++fm)
                    #pragma unroll
                    for (int fn = 0; fn < 2; ++fn)
                        c1[fm][fn] = __builtin_amdgcn_mfma_f32_16x16x32_bf16(
                            af[fm], bw[fn], c1[fm][fn], 0, 0, 0);
            }
        }
        // ---- +b1, GELU (tanh-approx: v*sigmoid(1.59577(v+0.044715 v^3)))
        #pragma unroll
        for (int fn = 0; fn < 2; ++fn) {
            const int colh = wn * 32 + fn * 16 + fr;
            const float b1v = b1[s * 128 + colh];
            #pragma unroll
            for (int fm = 0; fm < 2; ++fm) {
                #pragma unroll
                for (int r = 0; r < 4; ++r) {
                    const int mi = fm * 16 + kg * 4 + r;
                    const float v = c1[fm][fn][r] + b1v;
                    const float u = 1.5957691216057308f * (v + 0.044715f * v * v * v);
                    const float ge = v / (1.0f + __expf(-u));
                    HS[mi * 128 + ((colh >> 3) ^ (mi & 7)) * 8 + (colh & 7)] = f2bf(ge);
                }
            }
        }
        // ---- GEMM2: acc(32x256) += h(32x128) @ W2s^T, 4 stages of K=32
        for (int kt2 = 0; kt2 < 4; ++kt2) {
            __syncthreads();                     // HS published / SB free
            #pragma unroll
            for (int i = 0; i < 4; ++i) {        // stage B2 [256][32] = 16KB
                const int L = i * 256 + tid;     // 1024 slots of 16B
                const int row = L >> 2;          // 0..255
                const int sl = (L & 3) ^ ((row >> 1) & 3);
                gld16(w2b + (size_t)row * 1024 + s * 128 + kt2 * 32 + sl * 8,
                      &SB[(i * 256 + wbase) * 8]);
            }
            __syncthreads();
            bfrag af[2], bw[4];
            #pragma unroll
            for (int fm = 0; fm < 2; ++fm) {
                const int r = fm * 16 + fr;
                af[fm] = *(const bfrag*)&HS[r * 128 + (((kt2 * 4 + kg) ^ (r & 7)) * 8)];
            }
            #pragma unroll
            for (int fn = 0; fn < 4; ++fn) {
                const int r = wn * 64 + fn * 16 + fr;
                bw[fn] = *(const bfrag*)&SB[r * 32 + ((kg ^ ((r >> 1) & 3)) * 8)];
            }
            #pragma unroll
            for (int fm = 0; fm < 2; ++fm)
                #pragma unroll
                for (int fn = 0; fn < 4; ++fn)
                    acc[fm][fn] = __builtin_amdgcn_mfma_f32_16x16x32_bf16(
                        af[fm], bw[fn], acc[fm][fn], 0, 0, 0);
        }
        __syncthreads();                         // SB/HS readers done
    }

    // ---- epilogue: out = x1 + acc + b2
    #pragma unroll
    for (int fn = 0; fn < 4; ++fn) {
        const int col = wn * 64 + fn * 16 + fr;
        const float bv = b2[col];
        #pragma unroll
        for (int fm = 0; fm < 2; ++fm) {
            #pragma unroll
            for (int r = 0; r < 4; ++r) {
                const int mi = fm * 16 + kg * 4 + r;
                const size_t gi = (size_t)(grow0 + mi) * CDIM + col;
                io[gi] += acc[fm][fn][r] + bv;
            }
        }
    }
}

// ---------------------------------------------------------------------------
extern "C" void kernel_launch(void* const* d_in, const int* in_sizes, int n_in,
                              void* d_out, int out_size, void* d_ws, size_t ws_size,
                              hipStream_t stream)
{
    const float* x     = (const float*)d_in[0];
    const float* g1    = (const float*)d_in[1];
    const float* beta1 = (const float*)d_in[2];
    const float* wqkv  = (const float*)d_in[3];
    const float* bqkv  = (const float*)d_in[4];
    const float* btab  = (const float*)d_in[5];
    const float* wproj = (const float*)d_in[6];
    const float* bproj = (const float*)d_in[7];
    const float* g2    = (const float*)d_in[8];
    const float* beta2 = (const float*)d_in[9];
    const float* w1    = (const float*)d_in[10];
    const float* b1    = (const float*)d_in[11];
    const float* w2    = (const float*)d_in[12];
    const float* b2    = (const float*)d_in[13];
    const int*   wti   = (const int*)d_in[17];
    float* out = (float*)d_out;

    const size_t COMB_ELEMS = (size_t)8 * 8 * 81 * 256;                // 1327104
    const size_t WQKV_E = (size_t)C3 * CDIM, WP_E = (size_t)CDIM * CDIM;
    const size_t W1_E = (size_t)HID * CDIM,  W2_E = (size_t)CDIM * HID;
    const size_t base_bytes = COMB_ELEMS * 4
                            + (WQKV_E + WP_E + W1_E + W2_E) * 2;

    int nch = 32;
    for (int cand : {4, 8, 16, 32}) {
        const size_t rows = (size_t)L_TOK / cand;
        if (base_bytes + rows * (C3 + CDIM) * 2 <= ws_size) { nch = cand; break; }
    }
    const int wins_per = NWIN / nch;
    const int rows_per = wins_per * NTOK;

    char* wsp = (char*)d_ws;
    float* comb = (float*)wsp;   wsp += COMB_ELEMS * 4;
    ushort* wq_b = (ushort*)wsp; wsp += WQKV_E * 2;
    ushort* wp_b = (ushort*)wsp; wsp += WP_E * 2;
    ushort* w1_b = (ushort*)wsp; wsp += W1_E * 2;
    ushort* w2_b = (ushort*)wsp; wsp += W2_E * 2;
    ushort* ratt = (ushort*)wsp; wsp += (size_t)rows_per * CDIM * 2;  // xw/attn-out (shared)
    ushort* rbig = (ushort*)wsp;                 // rows_per * C3 bf16

    cvt_kernel<<<(int)(WQKV_E / 1024), 256, 0, stream>>>(wqkv, wq_b);
    cvt_kernel<<<(int)(WP_E   / 1024), 256, 0, stream>>>(wproj, wp_b);
    cvt_kernel<<<(int)(W1_E   / 1024), 256, 0, stream>>>(w1, w1_b);
    cvt_kernel<<<(int)(W2_E   / 1024), 256, 0, stream>>>(w2, w2_b);
    comb_pre_kernel<<<(int)(COMB_ELEMS / 256), 256, 0, stream>>>(btab, wti, comb);

    // Phase 1: LN1+shift (bf16, once) -> QKV -> attention -> proj(+reverse+roll+residual)
    for (int c = 0; c < nch; ++c) {
        const int row0 = c * rows_per;
        const int win0 = c * wins_per;
        ln1_kernel<<<rows_per / 4, 256, 0, stream>>>(x, g1, beta1, ratt, row0);
        mgemm<0><<<dim3(C3 / 128, rows_per / 128), 256, 0, stream>>>(
            ratt, wq_b, bqkv, rbig, nullptr, CDIM, row0);
        attn_kernel<<<wins_per * NHEADS, 64, 0, stream>>>(rbig, comb, ratt, win0);
        mgemm<1><<<dim3(CDIM / 128, rows_per / 128), 256, 0, stream>>>(
            ratt, wp_b, bproj, out, x, CDIM, row0);
    }

    // Phase 2: fused LN2 + MLP1 + GELU + MLP2 + residual (hidden stays on-chip)
    mlp_fused<<<L_TOK / 32, 256, 0, stream>>>(out, w1_b, b1, w2_b, b2, g2, beta2);
}

// Round 17
// 784.257 us; speedup vs baseline: 1.3972x; 1.1671x over previous
//
#include <hip/hip_runtime.h>
#include <hip/hip_bf16.h>
#include <math.h>

// Fixed instance: B=1, Z=8, H=96, W=192, C=256
#define L_TOK   147456
#define CDIM    256
#define C3      768
#define HID     1024
#define NWIN    1024
#define NTOK    144
#define NHEADS  8
#define HD      32
#define SCALE   0.1767766952966369f   // 1/sqrt(32)

typedef __attribute__((ext_vector_type(8))) short bfrag;   // 8 bf16 (4 VGPRs)
typedef __attribute__((ext_vector_type(4))) float f32x4;

__device__ __forceinline__ ushort f2bf(float f) {
    __hip_bfloat16 h = __float2bfloat16(f);
    return *reinterpret_cast<ushort*>(&h);
}
__device__ __forceinline__ float bf2f(ushort u) {
    __hip_bfloat16 h = *reinterpret_cast<__hip_bfloat16*>(&u);
    return __bfloat162float(h);
}

// async global->LDS, 16B per lane; LDS dest = wave-uniform base + lane*16
__device__ __forceinline__ void gld16(const ushort* g, ushort* l) {
    __builtin_amdgcn_global_load_lds(
        (const __attribute__((address_space(1))) void*)g,
        (__attribute__((address_space(3))) void*)l, 16, 0, 0);
}

// window-order row gt -> spatial token index (shift + partition map; also the
// inverse scatter target for window-reverse + roll-back)
__device__ __forceinline__ int shift_src(int gt) {
    const int win = gt / NTOK;
    const int nt  = gt - win * NTOK;
    const int wz = win >> 8, wh = (win >> 4) & 15, ww = win & 15;
    const int lz = nt / 72;
    const int t2 = nt - lz * 72;
    const int lh = t2 / 12, lw = t2 - lh * 12;
    const int z = (wz * 2 + lz + 1) & 7;
    int h = wh * 6 + lh + 3;  if (h >= 96)  h -= 96;
    int w = ww * 12 + lw + 6; if (w >= 192) w -= 192;
    return (z * 96 + h) * 192 + w;
}

// ---------------------------------------------------------------------------
// LN1 + shift + window-partition gather -> bf16 rows. One wave per row.
// ---------------------------------------------------------------------------
__global__ __launch_bounds__(256) void ln1_kernel(const float* __restrict__ x,
                                                  const float* __restrict__ g,
                                                  const float* __restrict__ b,
                                                  ushort* __restrict__ xw,
                                                  int row0)
{
    const int wave = threadIdx.x >> 6;
    const int lane = threadIdx.x & 63;
    const int t = blockIdx.x * 4 + wave;
    const int src = shift_src(row0 + t);
    const float4 xv = *(const float4*)(x + (size_t)src * CDIM + lane * 4);
    float s  = xv.x + xv.y + xv.z + xv.w;
    float ss = xv.x*xv.x + xv.y*xv.y + xv.z*xv.z + xv.w*xv.w;
    #pragma unroll
    for (int off = 32; off; off >>= 1) {
        s  += __shfl_xor(s,  off);
        ss += __shfl_xor(ss, off);
    }
    const float mean = s * (1.0f / CDIM);
    const float var  = ss * (1.0f / CDIM) - mean * mean;
    const float rstd = rsqrtf(var + 1e-5f);
    const float4 gv = *(const float4*)(g + lane * 4);
    const float4 bv = *(const float4*)(b + lane * 4);
    union { ushort u[4]; uint2 q; } pk;
    pk.u[0] = f2bf((xv.x - mean) * rstd * gv.x + bv.x);
    pk.u[1] = f2bf((xv.y - mean) * rstd * gv.y + bv.y);
    pk.u[2] = f2bf((xv.z - mean) * rstd * gv.z + bv.z);
    pk.u[3] = f2bf((xv.w - mean) * rstd * gv.w + bv.w);
    *(uint2*)(xw + (size_t)t * CDIM + lane * 4) = pk.q;
}

// ---------------------------------------------------------------------------
// fp32 -> bf16 convert for all four weight matrices in one launch.
// dst layout (contiguous): [wqkv | wproj | w1 | w2]
// Grid = 768 blocks x 256 thr, 4 elems/thr (1024/block).
// ---------------------------------------------------------------------------
__global__ __launch_bounds__(256) void cvt4_kernel(const float* __restrict__ wqkv,
                                                   const float* __restrict__ wproj,
                                                   const float* __restrict__ w1,
                                                   const float* __restrict__ w2,
                                                   ushort* __restrict__ dst)
{
    const int bid = blockIdx.x;
    const float* s;
    size_t dbase;
    int lbid;
    if (bid < 192)      { s = wqkv;  dbase = 0;                lbid = bid; }
    else if (bid < 256) { s = wproj; dbase = 196608;           lbid = bid - 192; }
    else if (bid < 512) { s = w1;    dbase = 196608 + 65536;   lbid = bid - 256; }
    else                { s = w2;    dbase = 196608 + 65536 + 262144; lbid = bid - 512; }
    const int i = lbid * 1024 + threadIdx.x * 4;
    const float4 v = *(const float4*)(s + i);
    ushort* d = dst + dbase;
    d[i + 0] = f2bf(v.x); d[i + 1] = f2bf(v.y);
    d[i + 2] = f2bf(v.z); d[i + 3] = f2bf(v.w);
}

// ---------------------------------------------------------------------------
// Combined bias+mask table, FP32, MFMA-fragment order:
//   comb[(((cls*8+h)*9+rb)*9+ct)*256 + lane*4 + reg]
// cls bits: (wz==3)<<2 | (wh==15)<<1 | (ww==15)
// ---------------------------------------------------------------------------
__global__ __launch_bounds__(256) void comb_pre_kernel(const float* __restrict__ bt,
                                                       const int* __restrict__ wti_p,
                                                       float* __restrict__ comb)
{
    const int e = blockIdx.x * 256 + threadIdx.x;   // < 8*8*81*256 = 1327104
    const int wti = *wti_p;
    const int reg  = e & 3;
    const int lane = (e >> 2) & 63;
    const int t    = e >> 8;
    const int ct = t % 9;
    const int rb = (t / 9) % 9;
    const int h  = (t / 81) % 8;
    const int cls = t / 648;
    const int i = rb * 16 + ((lane >> 4) << 2) + reg;
    const int j = ct * 16 + (lane & 15);
    const int zi = i / 72, ri = i - zi * 72, hi = ri / 12, wi = ri - (ri / 12) * 12;
    const int zj = j / 72, rj = j - zj * 72, hj = rj / 12, wj = rj - (rj / 12) * 12;
    const int idx = (zi + 2 * zj) * 828 + (hi + 6 * hj) * 23 + (wi - wj + 11);
    const float bias = bt[((size_t)idx * 64 + wti) * 8 + h];
    const int cz = (cls >> 2) & 1, ch = (cls >> 1) & 1, cw = cls & 1;
    const int ri_ = (cz ? (zi == 0 ? 1 : 2) : 0) * 9
                  + (ch ? (hi < 3 ? 1 : 2) : 0) * 3
                  + (cw ? (wi < 6 ? 1 : 2) : 0);
    const int rj_ = (cz ? (zj == 0 ? 1 : 2) : 0) * 9
                  + (ch ? (hj < 3 ? 1 : 2) : 0) * 3
                  + (cw ? (wj < 6 ? 1 : 2) : 0);
    comb[e] = bias + ((ri_ == rj_) ? 0.0f : -100.0f);
}

// ---------------------------------------------------------------------------
// MFMA attention: one wave per (local window, head). Q unscaled; SCALE applied
// in fp32 after QK^T (s = s*SCALE + bias).
// ---------------------------------------------------------------------------
__global__ __launch_bounds__(64) void attn_kernel(const ushort* __restrict__ qkv,
                                                  const float* __restrict__ comb,
                                                  ushort* __restrict__ outb,
                                                  int win0)
{
    __shared__ ushort vt[32][168];   // V^T, cols(j) padded: [144,160) zeroed
    __shared__ ushort pt[16][168];   // P tile, cols padded: [144,160) zeroed

    const int winl = blockIdx.x >> 3;
    const int head = blockIdx.x & 7;
    const int win  = win0 + winl;
    const int lane = threadIdx.x;
    const int g = lane >> 4, c = lane & 15;
    const int cls = (((win >> 8) == 3) ? 4 : 0)
                  | ((((win >> 4) & 15) == 15) ? 2 : 0)
                  | (((win & 15) == 15) ? 1 : 0);

    const ushort* qb = qkv + (((size_t)(winl * 3 + 0) * 8 + head) * NTOK) * HD;
    const ushort* kb = qkv + (((size_t)(winl * 3 + 1) * 8 + head) * NTOK) * HD;
    const ushort* vb = qkv + (((size_t)(winl * 3 + 2) * 8 + head) * NTOK) * HD;

    for (int i = lane; i < 512; i += 64) vt[i >> 4][144 + (i & 15)] = 0;
    for (int i = lane; i < 256; i += 64) pt[i >> 4][144 + (i & 15)] = 0;
    for (int base = lane * 8; base < NTOK * HD; base += 512) {
        const int j = base >> 5, d0 = base & 31;
        union { ushort u[8]; uint4 q; } tv;
        tv.q = *(const uint4*)(vb + base);
        #pragma unroll
        for (int e = 0; e < 8; ++e) vt[d0 + e][j] = tv.u[e];
    }
    __syncthreads();

    bfrag kf[9];
    #pragma unroll
    for (int ct = 0; ct < 9; ++ct)
        kf[ct] = *(const bfrag*)(kb + (size_t)(ct * 16 + c) * HD + g * 8);
    bfrag vf[2][5];
    #pragma unroll
    for (int nt = 0; nt < 2; ++nt)
        #pragma unroll
        for (int kt = 0; kt < 5; ++kt)
            vf[nt][kt] = *(const bfrag*)&vt[nt * 16 + c][kt * 32 + g * 8];

    const float* cb = comb + ((size_t)cls * 8 + head) * 81 * 256;

    for (int rb = 0; rb < 9; ++rb) {
        const bfrag aq = *(const bfrag*)(qb + (size_t)(rb * 16 + c) * HD + g * 8);
        f32x4 s[9];
        #pragma unroll
        for (int ct = 0; ct < 9; ++ct)
            s[ct] = __builtin_amdgcn_mfma_f32_16x16x32_bf16(
                aq, kf[ct], (f32x4){0.0f, 0.0f, 0.0f, 0.0f}, 0, 0, 0);

        // fp32 scale + bias + mask (fragment-ordered fp32 table, 16B/lane)
        #pragma unroll
        for (int ct = 0; ct < 9; ++ct) {
            const float4 bw = *(const float4*)(cb + (size_t)(rb * 9 + ct) * 256 + lane * 4);
            s[ct][0] = s[ct][0] * SCALE + bw.x;
            s[ct][1] = s[ct][1] * SCALE + bw.y;
            s[ct][2] = s[ct][2] * SCALE + bw.z;
            s[ct][3] = s[ct][3] * SCALE + bw.w;
        }

        float mx[4] = {-1e30f, -1e30f, -1e30f, -1e30f};
        #pragma unroll
        for (int ct = 0; ct < 9; ++ct)
            #pragma unroll
            for (int r = 0; r < 4; ++r) mx[r] = fmaxf(mx[r], s[ct][r]);
        #pragma unroll
        for (int off = 1; off < 16; off <<= 1)
            #pragma unroll
            for (int r = 0; r < 4; ++r) mx[r] = fmaxf(mx[r], __shfl_xor(mx[r], off));
        float sm[4] = {0.0f, 0.0f, 0.0f, 0.0f};
        #pragma unroll
        for (int ct = 0; ct < 9; ++ct)
            #pragma unroll
            for (int r = 0; r < 4; ++r) {
                const float e = __expf(s[ct][r] - mx[r]);
                s[ct][r] = e; sm[r] += e;
            }
        #pragma unroll
        for (int off = 1; off < 16; off <<= 1)
            #pragma unroll
            for (int r = 0; r < 4; ++r) sm[r] += __shfl_xor(sm[r], off);
        float inv[4];
        #pragma unroll
        for (int r = 0; r < 4; ++r) inv[r] = 1.0f / sm[r];

        #pragma unroll
        for (int ct = 0; ct < 9; ++ct)
            #pragma unroll
            for (int r = 0; r < 4; ++r)
                pt[g * 4 + r][ct * 16 + c] = f2bf(s[ct][r]);

        f32x4 o[2] = {(f32x4){0,0,0,0}, (f32x4){0,0,0,0}};
        #pragma unroll
        for (int kt = 0; kt < 5; ++kt) {
            const bfrag pa = *(const bfrag*)&pt[c][kt * 32 + g * 8];
            o[0] = __builtin_amdgcn_mfma_f32_16x16x32_bf16(pa, vf[0][kt], o[0], 0, 0, 0);
            o[1] = __builtin_amdgcn_mfma_f32_16x16x32_bf16(pa, vf[1][kt], o[1], 0, 0, 0);
        }

        const size_t ob = ((size_t)winl * NTOK + rb * 16 + g * 4) * CDIM + head * HD;
        #pragma unroll
        for (int nt = 0; nt < 2; ++nt)
            #pragma unroll
            for (int r = 0; r < 4; ++r)
                outb[ob + (size_t)r * CDIM + nt * 16 + c] = f2bf(o[nt][r] * inv[r]);
    }
}

// ---------------------------------------------------------------------------
// bf16 MFMA GEMM (phase-1): C = A(MxK) @ Bw(NxK)^T + bias. 128x128, BK=64.
// Grid: blockIdx.x = n-tile (fast), blockIdx.y = m-tile (A-panel L2-hot).
// EPI : 0 = QKV scatter (raw, no Q scale); 1 = proj+reverse+roll+residual
// ---------------------------------------------------------------------------
template<int EPI>
__global__ __launch_bounds__(256) void mgemm(const ushort* __restrict__ A,
                                             const ushort* __restrict__ Bw,
                                             const float* __restrict__ bias,
                                             void* __restrict__ outp,
                                             const float* __restrict__ resid,
                                             int K, int grow0)
{
    __shared__ __align__(16) ushort Asb[128 * 64];
    __shared__ __align__(16) ushort Bsb[128 * 64];

    const int tid = threadIdx.x;
    const int m0 = blockIdx.y * 128;
    const int n0 = blockIdx.x * 128;
    const int w = tid >> 6, lane = tid & 63;
    const int wm = w >> 1, wn = w & 1;
    const int fr = lane & 15, kg = lane >> 4;
    const int wbase = tid & 192;

    f32x4 acc[4][4];
    #pragma unroll
    for (int i = 0; i < 4; ++i)
        #pragma unroll
        for (int j = 0; j < 4; ++j)
            acc[i][j] = (f32x4){0.0f, 0.0f, 0.0f, 0.0f};

    int lrow[4], lsl[4];
    #pragma unroll
    for (int it = 0; it < 4; ++it) {
        const int s = it * 256 + tid;
        lrow[it] = s >> 3;
        lsl[it]  = ((s & 7) ^ (lrow[it] & 7)) * 8;
    }

    size_t aoff[4], boff[4];
    #pragma unroll
    for (int it = 0; it < 4; ++it) {
        aoff[it] = (size_t)(m0 + lrow[it]) * K;
        boff[it] = (size_t)(n0 + lrow[it]) * K;
    }

    for (int kt = 0; kt < K; kt += 64) {
        #pragma unroll
        for (int it = 0; it < 4; ++it)
            gld16(A + aoff[it] + kt + lsl[it], &Asb[(it * 256 + wbase) * 8]);
        #pragma unroll
        for (int it = 0; it < 4; ++it)
            gld16(Bw + boff[it] + kt + lsl[it], &Bsb[(it * 256 + wbase) * 8]);
        __syncthreads();

        #pragma unroll
        for (int kh = 0; kh < 2; ++kh) {
            bfrag af[4], bfv[4];
            #pragma unroll
            for (int fm = 0; fm < 4; ++fm) {
                const int r = wm * 64 + fm * 16 + fr;
                af[fm] = *(const bfrag*)&Asb[r * 64 + (((kh * 4 + kg) ^ (r & 7)) * 8)];
            }
            #pragma unroll
            for (int fn = 0; fn < 4; ++fn) {
                const int r = wn * 64 + fn * 16 + fr;
                bfv[fn] = *(const bfrag*)&Bsb[r * 64 + (((kh * 4 + kg) ^ (r & 7)) * 8)];
            }
            #pragma unroll
            for (int fm = 0; fm < 4; ++fm)
                #pragma unroll
                for (int fn = 0; fn < 4; ++fn)
                    acc[fm][fn] = __builtin_amdgcn_mfma_f32_16x16x32_bf16(
                        af[fm], bfv[fn], acc[fm][fn], 0, 0, 0);
        }
        __syncthreads();
    }

    #pragma unroll
    for (int fn = 0; fn < 4; ++fn) {
        const int col = n0 + wn * 64 + fn * 16 + fr;
        const float bv = bias[col];
        #pragma unroll
        for (int fm = 0; fm < 4; ++fm) {
            #pragma unroll
            for (int r = 0; r < 4; ++r) {
                const int mi = m0 + wm * 64 + fm * 16 + kg * 4 + r;
                float val = acc[fm][fn][r] + bv;
                if constexpr (EPI == 0) {
                    const int winl = mi / NTOK, nt = mi - (mi / NTOK) * NTOK;
                    const int sel = col >> 8, head = (col >> 5) & 7, d = col & 31;
                    ((ushort*)outp)[(((size_t)(winl * 3 + sel) * 8 + head) * NTOK + nt) * HD + d] = f2bf(val);
                } else {
                    const int p = shift_src(grow0 + mi);
                    ((float*)outp)[(size_t)p * CDIM + col] = resid[(size_t)p * CDIM + col] + val;
                }
            }
        }
    }
}

// ---------------------------------------------------------------------------
// Fused MLP (round-14 passing structure, verbatim; exact erff GELU): per
// block 32 rows of io. 256 thr (4 waves). LDS 40KB:
//   XS [32][256] 16KB | HS [32][128] 8KB | SB 16KB staging
// ---------------------------------------------------------------------------
__global__ __launch_bounds__(256) void mlp_fused(float* __restrict__ io,
                                                 const ushort* __restrict__ w1b,
                                                 const float* __restrict__ b1,
                                                 const ushort* __restrict__ w2b,
                                                 const float* __restrict__ b2,
                                                 const float* __restrict__ g2,
                                                 const float* __restrict__ beta2)
{
    __shared__ __align__(16) ushort lds[20480];   // 40KB
    ushort* XS = lds;            // 8192 ushorts: [32][256]
    ushort* HS = lds + 8192;     // 4096 ushorts: [32][128]
    ushort* SB = lds + 12288;    // 8192 ushorts: staging (16KB)

    const int tid = threadIdx.x;
    const int wn = tid >> 6, lane = tid & 63;
    const int fr = lane & 15, kg = lane >> 4;
    const int wbase = tid & 192;                 // wn*64, wave-uniform
    const int grow0 = blockIdx.x * 32;

    // ---- load x1 rows, LN2, pack bf16 -> XS (32 rows, 8 thr/row)
    {
        const int row = tid >> 3;
        const int oct = tid & 7;                 // 32 cols each
        const float* xr = io + (size_t)(grow0 + row) * CDIM + oct * 32;
        float4 v[8];
        float s = 0.0f, ss = 0.0f;
        #pragma unroll
        for (int j = 0; j < 8; ++j) {
            v[j] = *(const float4*)(xr + j * 4);
            s  += v[j].x + v[j].y + v[j].z + v[j].w;
            ss += v[j].x*v[j].x + v[j].y*v[j].y + v[j].z*v[j].z + v[j].w*v[j].w;
        }
        #pragma unroll
        for (int off = 1; off < 8; off <<= 1) {
            s  += __shfl_xor(s,  off);
            ss += __shfl_xor(ss, off);
        }
        const float mean = s * (1.0f / CDIM);
        const float var  = ss * (1.0f / CDIM) - mean * mean;
        const float rstd = rsqrtf(var + 1e-5f);
        #pragma unroll
        for (int j = 0; j < 4; ++j) {            // 4 slots of 8 elems
            const int c = oct * 32 + j * 8;
            const float4 ga = *(const float4*)(g2 + c);
            const float4 gb = *(const float4*)(g2 + c + 4);
            const float4 ba = *(const float4*)(beta2 + c);
            const float4 bb = *(const float4*)(beta2 + c + 4);
            union { ushort u[8]; uint4 q4; } pk;
            pk.u[0] = f2bf((v[2*j].x   - mean) * rstd * ga.x + ba.x);
            pk.u[1] = f2bf((v[2*j].y   - mean) * rstd * ga.y + ba.y);
            pk.u[2] = f2bf((v[2*j].z   - mean) * rstd * ga.z + ba.z);
            pk.u[3] = f2bf((v[2*j].w   - mean) * rstd * ga.w + ba.w);
            pk.u[4] = f2bf((v[2*j+1].x - mean) * rstd * gb.x + bb.x);
            pk.u[5] = f2bf((v[2*j+1].y - mean) * rstd * gb.y + bb.y);
            pk.u[6] = f2bf((v[2*j+1].z - mean) * rstd * gb.z + bb.z);
            pk.u[7] = f2bf((v[2*j+1].w - mean) * rstd * gb.w + bb.w);
            const int slot = oct * 4 + j;                 // 0..31
            *(uint4*)&XS[row * 256 + (slot ^ (row & 7)) * 8] = pk.q4;
        }
    }

    f32x4 acc[2][4];
    #pragma unroll
    for (int i = 0; i < 2; ++i)
        #pragma unroll
        for (int j = 0; j < 4; ++j)
            acc[i][j] = (f32x4){0.0f, 0.0f, 0.0f, 0.0f};

    for (int s = 0; s < 8; ++s) {                // hidden strips of 128
        // ---- GEMM1: C1(32x128) = X(32x256) @ W1s^T
        f32x4 c1[2][2];
        #pragma unroll
        for (int i = 0; i < 2; ++i) { c1[i][0] = (f32x4){0,0,0,0}; c1[i][1] = (f32x4){0,0,0,0}; }
        for (int kt = 0; kt < 4; ++kt) {         // BK=64 over K=256
            __syncthreads();                     // SB free (prev readers done)
            #pragma unroll
            for (int i = 0; i < 4; ++i) {        // stage B1 [128][64] = 16KB
                const int L = i * 256 + tid;     // 1024 slots of 16B
                const int row = L >> 3;
                const int sl = (L & 7) ^ (row & 7);
                gld16(w1b + (size_t)(s * 128 + row) * 256 + kt * 64 + sl * 8,
                      &SB[(i * 256 + wbase) * 8]);
            }
            __syncthreads();                     // loads drained + visible
            #pragma unroll
            for (int ks = 0; ks < 2; ++ks) {
                bfrag af[2], bw[2];
                #pragma unroll
                for (int fm = 0; fm < 2; ++fm) {
                    const int r = fm * 16 + fr;
                    const int slot = kt * 8 + ks * 4 + kg;
                    af[fm] = *(const bfrag*)&XS[r * 256 + (slot ^ (r & 7)) * 8];
                }
                #pragma unroll
                for (int fn = 0; fn < 2; ++fn) {
                    const int r = wn * 32 + fn * 16 + fr;
                    const int slot = ks * 4 + kg;
                    bw[fn] = *(const bfrag*)&SB[r * 64 + (slot ^ (r & 7)) * 8];
                }
                #pragma unroll
                for (int fm = 0; fm < 2; ++fm)
                    #pragma unroll
                    for (int fn = 0; fn < 2; ++fn)
                        c1[fm][fn] = __builtin_amdgcn_mfma_f32_16x16x32_bf16(
                            af[fm], bw[fn], c1[fm][fn], 0, 0, 0);
            }
        }
        // ---- +b1, GELU (exact erf), plain writes to HS
        #pragma unroll
        for (int fn = 0; fn < 2; ++fn) {
            const int colh = wn * 32 + fn * 16 + fr;
            const float b1v = b1[s * 128 + colh];
            #pragma unroll
            for (int fm = 0; fm < 2; ++fm) {
                #pragma unroll
                for (int r = 0; r < 4; ++r) {
                    const int mi = fm * 16 + kg * 4 + r;
                    const float v = c1[fm][fn][r] + b1v;
                    const float ge = 0.5f * v * (1.0f + erff(v * 0.70710678118654752f));
                    HS[mi * 128 + ((colh >> 3) ^ (mi & 7)) * 8 + (colh & 7)] = f2bf(ge);
                }
            }
        }
        // ---- GEMM2: acc(32x256) += h(32x128) @ W2s^T, 4 stages of K=32
        for (int kt2 = 0; kt2 < 4; ++kt2) {
            __syncthreads();                     // HS published / SB free
            #pragma unroll
            for (int i = 0; i < 4; ++i) {        // stage B2 [256][32] = 16KB
                const int L = i * 256 + tid;     // 1024 slots of 16B
                const int row = L >> 2;          // 0..255
                const int sl = (L & 3) ^ ((row >> 1) & 3);
                gld16(w2b + (size_t)row * 1024 + s * 128 + kt2 * 32 + sl * 8,
                      &SB[(i * 256 + wbase) * 8]);
            }
            __syncthreads();
            bfrag af[2], bw[4];
            #pragma unroll
            for (int fm = 0; fm < 2; ++fm) {
                const int r = fm * 16 + fr;
                af[fm] = *(const bfrag*)&HS[r * 128 + (((kt2 * 4 + kg) ^ (r & 7)) * 8)];
            }
            #pragma unroll
            for (int fn = 0; fn < 4; ++fn) {
                const int r = wn * 64 + fn * 16 + fr;
                bw[fn] = *(const bfrag*)&SB[r * 32 + ((kg ^ ((r >> 1) & 3)) * 8)];
            }
            #pragma unroll
            for (int fm = 0; fm < 2; ++fm)
                #pragma unroll
                for (int fn = 0; fn < 4; ++fn)
                    acc[fm][fn] = __builtin_amdgcn_mfma_f32_16x16x32_bf16(
                        af[fm], bw[fn], acc[fm][fn], 0, 0, 0);
        }
        __syncthreads();                         // SB/HS readers done
    }

    // ---- epilogue: out = x1 + acc + b2
    #pragma unroll
    for (int fn = 0; fn < 4; ++fn) {
        const int col = wn * 64 + fn * 16 + fr;
        const float bv = b2[col];
        #pragma unroll
        for (int fm = 0; fm < 2; ++fm) {
            #pragma unroll
            for (int r = 0; r < 4; ++r) {
                const int mi = fm * 16 + kg * 4 + r;
                const size_t gi = (size_t)(grow0 + mi) * CDIM + col;
                io[gi] += acc[fm][fn][r] + bv;
            }
        }
    }
}

// ---------------------------------------------------------------------------
extern "C" void kernel_launch(void* const* d_in, const int* in_sizes, int n_in,
                              void* d_out, int out_size, void* d_ws, size_t ws_size,
                              hipStream_t stream)
{
    const float* x     = (const float*)d_in[0];
    const float* g1    = (const float*)d_in[1];
    const float* beta1 = (const float*)d_in[2];
    const float* wqkv  = (const float*)d_in[3];
    const float* bqkv  = (const float*)d_in[4];
    const float* btab  = (const float*)d_in[5];
    const float* wproj = (const float*)d_in[6];
    const float* bproj = (const float*)d_in[7];
    const float* g2    = (const float*)d_in[8];
    const float* beta2 = (const float*)d_in[9];
    const float* w1    = (const float*)d_in[10];
    const float* b1    = (const float*)d_in[11];
    const float* w2    = (const float*)d_in[12];
    const float* b2    = (const float*)d_in[13];
    const int*   wti   = (const int*)d_in[17];
    float* out = (float*)d_out;

    const size_t COMB_ELEMS = (size_t)8 * 8 * 81 * 256;                // 1327104
    const size_t WQKV_E = (size_t)C3 * CDIM, WP_E = (size_t)CDIM * CDIM;
    const size_t W1_E = (size_t)HID * CDIM,  W2_E = (size_t)CDIM * HID;
    const size_t base_bytes = COMB_ELEMS * 4
                            + (WQKV_E + WP_E + W1_E + W2_E) * 2;

    int nch = 32;
    for (int cand : {4, 8, 16, 32}) {
        const size_t rows = (size_t)L_TOK / cand;
        if (base_bytes + rows * (C3 + CDIM) * 2 <= ws_size) { nch = cand; break; }
    }
    const int wins_per = NWIN / nch;
    const int rows_per = wins_per * NTOK;

    char* wsp = (char*)d_ws;
    float* comb = (float*)wsp;   wsp += COMB_ELEMS * 4;
    ushort* wall = (ushort*)wsp; wsp += (WQKV_E + WP_E + W1_E + W2_E) * 2;
    ushort* wq_b = wall;
    ushort* wp_b = wall + WQKV_E;
    ushort* w1_b = wall + WQKV_E + WP_E;
    ushort* w2_b = wall + WQKV_E + WP_E + W1_E;
    ushort* ratt = (ushort*)wsp; wsp += (size_t)rows_per * CDIM * 2;  // xw/attn-out (shared)
    ushort* rbig = (ushort*)wsp;                 // rows_per * C3 bf16

    cvt4_kernel<<<768, 256, 0, stream>>>(wqkv, wproj, w1, w2, wall);
    comb_pre_kernel<<<(int)(COMB_ELEMS / 256), 256, 0, stream>>>(btab, wti, comb);

    // Phase 1: LN1+shift (bf16, once) -> QKV -> attention -> proj(+reverse+roll+residual)
    for (int c = 0; c < nch; ++c) {
        const int row0 = c * rows_per;
        const int win0 = c * wins_per;
        ln1_kernel<<<rows_per / 4, 256, 0, stream>>>(x, g1, beta1, ratt, row0);
        mgemm<0><<<dim3(C3 / 128, rows_per / 128), 256, 0, stream>>>(
            ratt, wq_b, bqkv, rbig, nullptr, CDIM, row0);
        attn_kernel<<<wins_per * NHEADS, 64, 0, stream>>>(rbig, comb, ratt, win0);
        mgemm<1><<<dim3(CDIM / 128, rows_per / 128), 256, 0, stream>>>(
            ratt, wp_b, bproj, out, x, CDIM, row0);
    }

    // Phase 2: fused LN2 + MLP1 + GELU + MLP2 + residual (hidden stays on-chip)
    mlp_fused<<<L_TOK / 32, 256, 0, stream>>>(out, w1_b, b1, w2_b, b2, g2, beta2);
}

// Round 18
// 748.859 us; speedup vs baseline: 1.4632x; 1.0473x over previous
//
#include <hip/hip_runtime.h>
#include <hip/hip_bf16.h>
#include <math.h>

// Fixed instance: B=1, Z=8, H=96, W=192, C=256
#define L_TOK   147456
#define CDIM    256
#define C3      768
#define HID     1024
#define NWIN    1024
#define NTOK    144
#define NHEADS  8
#define HD      32
#define SCALE   0.1767766952966369f   // 1/sqrt(32)

typedef __attribute__((ext_vector_type(8))) short bfrag;   // 8 bf16 (4 VGPRs)
typedef __attribute__((ext_vector_type(4))) float f32x4;

__device__ __forceinline__ ushort f2bf(float f) {
    __hip_bfloat16 h = __float2bfloat16(f);
    return *reinterpret_cast<ushort*>(&h);
}
__device__ __forceinline__ float bf2f(ushort u) {
    __hip_bfloat16 h = *reinterpret_cast<__hip_bfloat16*>(&u);
    return __bfloat162float(h);
}

// async global->LDS, 16B per lane; LDS dest = wave-uniform base + lane*16
__device__ __forceinline__ void gld16(const ushort* g, ushort* l) {
    __builtin_amdgcn_global_load_lds(
        (const __attribute__((address_space(1))) void*)g,
        (__attribute__((address_space(3))) void*)l, 16, 0, 0);
}

// window-order row gt -> spatial token index (shift + partition map; also the
// inverse scatter target for window-reverse + roll-back)
__device__ __forceinline__ int shift_src(int gt) {
    const int win = gt / NTOK;
    const int nt  = gt - win * NTOK;
    const int wz = win >> 8, wh = (win >> 4) & 15, ww = win & 15;
    const int lz = nt / 72;
    const int t2 = nt - lz * 72;
    const int lh = t2 / 12, lw = t2 - lh * 12;
    const int z = (wz * 2 + lz + 1) & 7;
    int h = wh * 6 + lh + 3;  if (h >= 96)  h -= 96;
    int w = ww * 12 + lw + 6; if (w >= 192) w -= 192;
    return (z * 96 + h) * 192 + w;
}

// ---------------------------------------------------------------------------
// LN1 + shift + window-partition gather -> bf16 rows. One wave per row.
// ---------------------------------------------------------------------------
__global__ __launch_bounds__(256) void ln1_kernel(const float* __restrict__ x,
                                                  const float* __restrict__ g,
                                                  const float* __restrict__ b,
                                                  ushort* __restrict__ xw,
                                                  int row0)
{
    const int wave = threadIdx.x >> 6;
    const int lane = threadIdx.x & 63;
    const int t = blockIdx.x * 4 + wave;
    const int src = shift_src(row0 + t);
    const float4 xv = *(const float4*)(x + (size_t)src * CDIM + lane * 4);
    float s  = xv.x + xv.y + xv.z + xv.w;
    float ss = xv.x*xv.x + xv.y*xv.y + xv.z*xv.z + xv.w*xv.w;
    #pragma unroll
    for (int off = 32; off; off >>= 1) {
        s  += __shfl_xor(s,  off);
        ss += __shfl_xor(ss, off);
    }
    const float mean = s * (1.0f / CDIM);
    const float var  = ss * (1.0f / CDIM) - mean * mean;
    const float rstd = rsqrtf(var + 1e-5f);
    const float4 gv = *(const float4*)(g + lane * 4);
    const float4 bv = *(const float4*)(b + lane * 4);
    union { ushort u[4]; uint2 q; } pk;
    pk.u[0] = f2bf((xv.x - mean) * rstd * gv.x + bv.x);
    pk.u[1] = f2bf((xv.y - mean) * rstd * gv.y + bv.y);
    pk.u[2] = f2bf((xv.z - mean) * rstd * gv.z + bv.z);
    pk.u[3] = f2bf((xv.w - mean) * rstd * gv.w + bv.w);
    *(uint2*)(xw + (size_t)t * CDIM + lane * 4) = pk.q;
}

// ---------------------------------------------------------------------------
// fp32 -> bf16 convert for all four weight matrices in one launch.
// dst layout (contiguous): [wqkv | wproj | w1 | w2]
// Grid = 768 blocks x 256 thr, 4 elems/thr (1024/block).
// ---------------------------------------------------------------------------
__global__ __launch_bounds__(256) void cvt4_kernel(const float* __restrict__ wqkv,
                                                   const float* __restrict__ wproj,
                                                   const float* __restrict__ w1,
                                                   const float* __restrict__ w2,
                                                   ushort* __restrict__ dst)
{
    const int bid = blockIdx.x;
    const float* s;
    size_t dbase;
    int lbid;
    if (bid < 192)      { s = wqkv;  dbase = 0;                lbid = bid; }
    else if (bid < 256) { s = wproj; dbase = 196608;           lbid = bid - 192; }
    else if (bid < 512) { s = w1;    dbase = 196608 + 65536;   lbid = bid - 256; }
    else                { s = w2;    dbase = 196608 + 65536 + 262144; lbid = bid - 512; }
    const int i = lbid * 1024 + threadIdx.x * 4;
    const float4 v = *(const float4*)(s + i);
    ushort* d = dst + dbase;
    d[i + 0] = f2bf(v.x); d[i + 1] = f2bf(v.y);
    d[i + 2] = f2bf(v.z); d[i + 3] = f2bf(v.w);
}

// ---------------------------------------------------------------------------
// Combined bias+mask table, FP32, MFMA-fragment order:
//   comb[(((cls*8+h)*9+rb)*9+ct)*256 + lane*4 + reg]
// cls bits: (wz==3)<<2 | (wh==15)<<1 | (ww==15)
// ---------------------------------------------------------------------------
__global__ __launch_bounds__(256) void comb_pre_kernel(const float* __restrict__ bt,
                                                       const int* __restrict__ wti_p,
                                                       float* __restrict__ comb)
{
    const int e = blockIdx.x * 256 + threadIdx.x;   // < 8*8*81*256 = 1327104
    const int wti = *wti_p;
    const int reg  = e & 3;
    const int lane = (e >> 2) & 63;
    const int t    = e >> 8;
    const int ct = t % 9;
    const int rb = (t / 9) % 9;
    const int h  = (t / 81) % 8;
    const int cls = t / 648;
    const int i = rb * 16 + ((lane >> 4) << 2) + reg;
    const int j = ct * 16 + (lane & 15);
    const int zi = i / 72, ri = i - zi * 72, hi = ri / 12, wi = ri - (ri / 12) * 12;
    const int zj = j / 72, rj = j - zj * 72, hj = rj / 12, wj = rj - (rj / 12) * 12;
    const int idx = (zi + 2 * zj) * 828 + (hi + 6 * hj) * 23 + (wi - wj + 11);
    const float bias = bt[((size_t)idx * 64 + wti) * 8 + h];
    const int cz = (cls >> 2) & 1, ch = (cls >> 1) & 1, cw = cls & 1;
    const int ri_ = (cz ? (zi == 0 ? 1 : 2) : 0) * 9
                  + (ch ? (hi < 3 ? 1 : 2) : 0) * 3
                  + (cw ? (wi < 6 ? 1 : 2) : 0);
    const int rj_ = (cz ? (zj == 0 ? 1 : 2) : 0) * 9
                  + (ch ? (hj < 3 ? 1 : 2) : 0) * 3
                  + (cw ? (wj < 6 ? 1 : 2) : 0);
    comb[e] = bias + ((ri_ == rj_) ? 0.0f : -100.0f);
}

// ---------------------------------------------------------------------------
// MFMA attention: one wave per (local window, head). Q unscaled; SCALE applied
// in fp32 after QK^T (s = s*SCALE + bias).
// ---------------------------------------------------------------------------
__global__ __launch_bounds__(64) void attn_kernel(const ushort* __restrict__ qkv,
                                                  const float* __restrict__ comb,
                                                  ushort* __restrict__ outb,
                                                  int win0)
{
    __shared__ ushort vt[32][168];   // V^T, cols(j) padded: [144,160) zeroed
    __shared__ ushort pt[16][168];   // P tile, cols padded: [144,160) zeroed

    const int winl = blockIdx.x >> 3;
    const int head = blockIdx.x & 7;
    const int win  = win0 + winl;
    const int lane = threadIdx.x;
    const int g = lane >> 4, c = lane & 15;
    const int cls = (((win >> 8) == 3) ? 4 : 0)
                  | ((((win >> 4) & 15) == 15) ? 2 : 0)
                  | (((win & 15) == 15) ? 1 : 0);

    const ushort* qb = qkv + (((size_t)(winl * 3 + 0) * 8 + head) * NTOK) * HD;
    const ushort* kb = qkv + (((size_t)(winl * 3 + 1) * 8 + head) * NTOK) * HD;
    const ushort* vb = qkv + (((size_t)(winl * 3 + 2) * 8 + head) * NTOK) * HD;

    for (int i = lane; i < 512; i += 64) vt[i >> 4][144 + (i & 15)] = 0;
    for (int i = lane; i < 256; i += 64) pt[i >> 4][144 + (i & 15)] = 0;
    for (int base = lane * 8; base < NTOK * HD; base += 512) {
        const int j = base >> 5, d0 = base & 31;
        union { ushort u[8]; uint4 q; } tv;
        tv.q = *(const uint4*)(vb + base);
        #pragma unroll
        for (int e = 0; e < 8; ++e) vt[d0 + e][j] = tv.u[e];
    }
    __syncthreads();

    bfrag kf[9];
    #pragma unroll
    for (int ct = 0; ct < 9; ++ct)
        kf[ct] = *(const bfrag*)(kb + (size_t)(ct * 16 + c) * HD + g * 8);
    bfrag vf[2][5];
    #pragma unroll
    for (int nt = 0; nt < 2; ++nt)
        #pragma unroll
        for (int kt = 0; kt < 5; ++kt)
            vf[nt][kt] = *(const bfrag*)&vt[nt * 16 + c][kt * 32 + g * 8];

    const float* cb = comb + ((size_t)cls * 8 + head) * 81 * 256;

    for (int rb = 0; rb < 9; ++rb) {
        const bfrag aq = *(const bfrag*)(qb + (size_t)(rb * 16 + c) * HD + g * 8);
        f32x4 s[9];
        #pragma unroll
        for (int ct = 0; ct < 9; ++ct)
            s[ct] = __builtin_amdgcn_mfma_f32_16x16x32_bf16(
                aq, kf[ct], (f32x4){0.0f, 0.0f, 0.0f, 0.0f}, 0, 0, 0);

        // fp32 scale + bias + mask (fragment-ordered fp32 table, 16B/lane)
        #pragma unroll
        for (int ct = 0; ct < 9; ++ct) {
            const float4 bw = *(const float4*)(cb + (size_t)(rb * 9 + ct) * 256 + lane * 4);
            s[ct][0] = s[ct][0] * SCALE + bw.x;
            s[ct][1] = s[ct][1] * SCALE + bw.y;
            s[ct][2] = s[ct][2] * SCALE + bw.z;
            s[ct][3] = s[ct][3] * SCALE + bw.w;
        }

        float mx[4] = {-1e30f, -1e30f, -1e30f, -1e30f};
        #pragma unroll
        for (int ct = 0; ct < 9; ++ct)
            #pragma unroll
            for (int r = 0; r < 4; ++r) mx[r] = fmaxf(mx[r], s[ct][r]);
        #pragma unroll
        for (int off = 1; off < 16; off <<= 1)
            #pragma unroll
            for (int r = 0; r < 4; ++r) mx[r] = fmaxf(mx[r], __shfl_xor(mx[r], off));
        float sm[4] = {0.0f, 0.0f, 0.0f, 0.0f};
        #pragma unroll
        for (int ct = 0; ct < 9; ++ct)
            #pragma unroll
            for (int r = 0; r < 4; ++r) {
                const float e = __expf(s[ct][r] - mx[r]);
                s[ct][r] = e; sm[r] += e;
            }
        #pragma unroll
        for (int off = 1; off < 16; off <<= 1)
            #pragma unroll
            for (int r = 0; r < 4; ++r) sm[r] += __shfl_xor(sm[r], off);
        float inv[4];
        #pragma unroll
        for (int r = 0; r < 4; ++r) inv[r] = 1.0f / sm[r];

        #pragma unroll
        for (int ct = 0; ct < 9; ++ct)
            #pragma unroll
            for (int r = 0; r < 4; ++r)
                pt[g * 4 + r][ct * 16 + c] = f2bf(s[ct][r]);

        f32x4 o[2] = {(f32x4){0,0,0,0}, (f32x4){0,0,0,0}};
        #pragma unroll
        for (int kt = 0; kt < 5; ++kt) {
            const bfrag pa = *(const bfrag*)&pt[c][kt * 32 + g * 8];
            o[0] = __builtin_amdgcn_mfma_f32_16x16x32_bf16(pa, vf[0][kt], o[0], 0, 0, 0);
            o[1] = __builtin_amdgcn_mfma_f32_16x16x32_bf16(pa, vf[1][kt], o[1], 0, 0, 0);
        }

        const size_t ob = ((size_t)winl * NTOK + rb * 16 + g * 4) * CDIM + head * HD;
        #pragma unroll
        for (int nt = 0; nt < 2; ++nt)
            #pragma unroll
            for (int r = 0; r < 4; ++r)
                outb[ob + (size_t)r * CDIM + nt * 16 + c] = f2bf(o[nt][r] * inv[r]);
    }
}

// ---------------------------------------------------------------------------
// bf16 MFMA GEMM (phase-1): C = A(MxK) @ Bw(NxK)^T + bias. 128x128, BK=64.
// Grid: blockIdx.x = n-tile (fast), blockIdx.y = m-tile (A-panel L2-hot).
// EPI : 0 = QKV scatter (raw, no Q scale); 1 = proj+reverse+roll+residual
// ---------------------------------------------------------------------------
template<int EPI>
__global__ __launch_bounds__(256) void mgemm(const ushort* __restrict__ A,
                                             const ushort* __restrict__ Bw,
                                             const float* __restrict__ bias,
                                             void* __restrict__ outp,
                                             const float* __restrict__ resid,
                                             int K, int grow0)
{
    __shared__ __align__(16) ushort Asb[128 * 64];
    __shared__ __align__(16) ushort Bsb[128 * 64];

    const int tid = threadIdx.x;
    const int m0 = blockIdx.y * 128;
    const int n0 = blockIdx.x * 128;
    const int w = tid >> 6, lane = tid & 63;
    const int wm = w >> 1, wn = w & 1;
    const int fr = lane & 15, kg = lane >> 4;
    const int wbase = tid & 192;

    f32x4 acc[4][4];
    #pragma unroll
    for (int i = 0; i < 4; ++i)
        #pragma unroll
        for (int j = 0; j < 4; ++j)
            acc[i][j] = (f32x4){0.0f, 0.0f, 0.0f, 0.0f};

    int lrow[4], lsl[4];
    #pragma unroll
    for (int it = 0; it < 4; ++it) {
        const int s = it * 256 + tid;
        lrow[it] = s >> 3;
        lsl[it]  = ((s & 7) ^ (lrow[it] & 7)) * 8;
    }

    size_t aoff[4], boff[4];
    #pragma unroll
    for (int it = 0; it < 4; ++it) {
        aoff[it] = (size_t)(m0 + lrow[it]) * K;
        boff[it] = (size_t)(n0 + lrow[it]) * K;
    }

    for (int kt = 0; kt < K; kt += 64) {
        #pragma unroll
        for (int it = 0; it < 4; ++it)
            gld16(A + aoff[it] + kt + lsl[it], &Asb[(it * 256 + wbase) * 8]);
        #pragma unroll
        for (int it = 0; it < 4; ++it)
            gld16(Bw + boff[it] + kt + lsl[it], &Bsb[(it * 256 + wbase) * 8]);
        __syncthreads();

        #pragma unroll
        for (int kh = 0; kh < 2; ++kh) {
            bfrag af[4], bfv[4];
            #pragma unroll
            for (int fm = 0; fm < 4; ++fm) {
                const int r = wm * 64 + fm * 16 + fr;
                af[fm] = *(const bfrag*)&Asb[r * 64 + (((kh * 4 + kg) ^ (r & 7)) * 8)];
            }
            #pragma unroll
            for (int fn = 0; fn < 4; ++fn) {
                const int r = wn * 64 + fn * 16 + fr;
                bfv[fn] = *(const bfrag*)&Bsb[r * 64 + (((kh * 4 + kg) ^ (r & 7)) * 8)];
            }
            #pragma unroll
            for (int fm = 0; fm < 4; ++fm)
                #pragma unroll
                for (int fn = 0; fn < 4; ++fn)
                    acc[fm][fn] = __builtin_amdgcn_mfma_f32_16x16x32_bf16(
                        af[fm], bfv[fn], acc[fm][fn], 0, 0, 0);
        }
        __syncthreads();
    }

    #pragma unroll
    for (int fn = 0; fn < 4; ++fn) {
        const int col = n0 + wn * 64 + fn * 16 + fr;
        const float bv = bias[col];
        #pragma unroll
        for (int fm = 0; fm < 4; ++fm) {
            #pragma unroll
            for (int r = 0; r < 4; ++r) {
                const int mi = m0 + wm * 64 + fm * 16 + kg * 4 + r;
                float val = acc[fm][fn][r] + bv;
                if constexpr (EPI == 0) {
                    const int winl = mi / NTOK, nt = mi - (mi / NTOK) * NTOK;
                    const int sel = col >> 8, head = (col >> 5) & 7, d = col & 31;
                    ((ushort*)outp)[(((size_t)(winl * 3 + sel) * 8 + head) * NTOK + nt) * HD + d] = f2bf(val);
                } else {
                    const int p = shift_src(grow0 + mi);
                    ((float*)outp)[(size_t)p * CDIM + col] = resid[(size_t)p * CDIM + col] + val;
                }
            }
        }
    }
}

// ---------------------------------------------------------------------------
// Fused MLP (round-14/17 passing structure; exact erff GELU): per block 32
// rows of io. 256 thr (4 waves). LDS 40KB -> 4 blocks/CU (launch_bounds
// occupancy hint; VGPR 84 <= 128 cap so codegen unchanged):
//   XS [32][256] 16KB | HS [32][128] 8KB | SB 16KB staging
// ---------------------------------------------------------------------------
__global__ __launch_bounds__(256, 4) void mlp_fused(float* __restrict__ io,
                                                    const ushort* __restrict__ w1b,
                                                    const float* __restrict__ b1,
                                                    const ushort* __restrict__ w2b,
                                                    const float* __restrict__ b2,
                                                    const float* __restrict__ g2,
                                                    const float* __restrict__ beta2)
{
    __shared__ __align__(16) ushort lds[20480];   // 40KB
    ushort* XS = lds;            // 8192 ushorts: [32][256]
    ushort* HS = lds + 8192;     // 4096 ushorts: [32][128]
    ushort* SB = lds + 12288;    // 8192 ushorts: staging (16KB)

    const int tid = threadIdx.x;
    const int wn = tid >> 6, lane = tid & 63;
    const int fr = lane & 15, kg = lane >> 4;
    const int wbase = tid & 192;                 // wn*64, wave-uniform
    const int grow0 = blockIdx.x * 32;

    // ---- load x1 rows, LN2, pack bf16 -> XS (32 rows, 8 thr/row)
    {
        const int row = tid >> 3;
        const int oct = tid & 7;                 // 32 cols each
        const float* xr = io + (size_t)(grow0 + row) * CDIM + oct * 32;
        float4 v[8];
        float s = 0.0f, ss = 0.0f;
        #pragma unroll
        for (int j = 0; j < 8; ++j) {
            v[j] = *(const float4*)(xr + j * 4);
            s  += v[j].x + v[j].y + v[j].z + v[j].w;
            ss += v[j].x*v[j].x + v[j].y*v[j].y + v[j].z*v[j].z + v[j].w*v[j].w;
        }
        #pragma unroll
        for (int off = 1; off < 8; off <<= 1) {
            s  += __shfl_xor(s,  off);
            ss += __shfl_xor(ss, off);
        }
        const float mean = s * (1.0f / CDIM);
        const float var  = ss * (1.0f / CDIM) - mean * mean;
        const float rstd = rsqrtf(var + 1e-5f);
        #pragma unroll
        for (int j = 0; j < 4; ++j) {            // 4 slots of 8 elems
            const int c = oct * 32 + j * 8;
            const float4 ga = *(const float4*)(g2 + c);
            const float4 gb = *(const float4*)(g2 + c + 4);
            const float4 ba = *(const float4*)(beta2 + c);
            const float4 bb = *(const float4*)(beta2 + c + 4);
            union { ushort u[8]; uint4 q4; } pk;
            pk.u[0] = f2bf((v[2*j].x   - mean) * rstd * ga.x + ba.x);
            pk.u[1] = f2bf((v[2*j].y   - mean) * rstd * ga.y + ba.y);
            pk.u[2] = f2bf((v[2*j].z   - mean) * rstd * ga.z + ba.z);
            pk.u[3] = f2bf((v[2*j].w   - mean) * rstd * ga.w + ba.w);
            pk.u[4] = f2bf((v[2*j+1].x - mean) * rstd * gb.x + bb.x);
            pk.u[5] = f2bf((v[2*j+1].y - mean) * rstd * gb.y + bb.y);
            pk.u[6] = f2bf((v[2*j+1].z - mean) * rstd * gb.z + bb.z);
            pk.u[7] = f2bf((v[2*j+1].w - mean) * rstd * gb.w + bb.w);
            const int slot = oct * 4 + j;                 // 0..31
            *(uint4*)&XS[row * 256 + (slot ^ (row & 7)) * 8] = pk.q4;
        }
    }

    f32x4 acc[2][4];
    #pragma unroll
    for (int i = 0; i < 2; ++i)
        #pragma unroll
        for (int j = 0; j < 4; ++j)
            acc[i][j] = (f32x4){0.0f, 0.0f, 0.0f, 0.0f};

    for (int s = 0; s < 8; ++s) {                // hidden strips of 128
        // ---- GEMM1: C1(32x128) = X(32x256) @ W1s^T
        f32x4 c1[2][2];
        #pragma unroll
        for (int i = 0; i < 2; ++i) { c1[i][0] = (f32x4){0,0,0,0}; c1[i][1] = (f32x4){0,0,0,0}; }
        for (int kt = 0; kt < 4; ++kt) {         // BK=64 over K=256
            __syncthreads();                     // SB free (prev readers done)
            #pragma unroll
            for (int i = 0; i < 4; ++i) {        // stage B1 [128][64] = 16KB
                const int L = i * 256 + tid;     // 1024 slots of 16B
                const int row = L >> 3;
                const int sl = (L & 7) ^ (row & 7);
                gld16(w1b + (size_t)(s * 128 + row) * 256 + kt * 64 + sl * 8,
                      &SB[(i * 256 + wbase) * 8]);
            }
            __syncthreads();                     // loads drained + visible
            #pragma unroll
            for (int ks = 0; ks < 2; ++ks) {
                bfrag af[2], bw[2];
                #pragma unroll
                for (int fm = 0; fm < 2; ++fm) {
                    const int r = fm * 16 + fr;
                    const int slot = kt * 8 + ks * 4 + kg;
                    af[fm] = *(const bfrag*)&XS[r * 256 + (slot ^ (r & 7)) * 8];
                }
                #pragma unroll
                for (int fn = 0; fn < 2; ++fn) {
                    const int r = wn * 32 + fn * 16 + fr;
                    const int slot = ks * 4 + kg;
                    bw[fn] = *(const bfrag*)&SB[r * 64 + (slot ^ (r & 7)) * 8];
                }
                #pragma unroll
                for (int fm = 0; fm < 2; ++fm)
                    #pragma unroll
                    for (int fn = 0; fn < 2; ++fn)
                        c1[fm][fn] = __builtin_amdgcn_mfma_f32_16x16x32_bf16(
                            af[fm], bw[fn], c1[fm][fn], 0, 0, 0);
            }
        }
        // ---- +b1, GELU (exact erf), plain writes to HS
        #pragma unroll
        for (int fn = 0; fn < 2; ++fn) {
            const int colh = wn * 32 + fn * 16 + fr;
            const float b1v = b1[s * 128 + colh];
            #pragma unroll
            for (int fm = 0; fm < 2; ++fm) {
                #pragma unroll
                for (int r = 0; r < 4; ++r) {
                    const int mi = fm * 16 + kg * 4 + r;
                    const float v = c1[fm][fn][r] + b1v;
                    const float ge = 0.5f * v * (1.0f + erff(v * 0.70710678118654752f));
                    HS[mi * 128 + ((colh >> 3) ^ (mi & 7)) * 8 + (colh & 7)] = f2bf(ge);
                }
            }
        }
        // ---- GEMM2: acc(32x256) += h(32x128) @ W2s^T, 4 stages of K=32
        for (int kt2 = 0; kt2 < 4; ++kt2) {
            __syncthreads();                     // HS published / SB free
            #pragma unroll
            for (int i = 0; i < 4; ++i) {        // stage B2 [256][32] = 16KB
                const int L = i * 256 + tid;     // 1024 slots of 16B
                const int row = L >> 2;          // 0..255
                const int sl = (L & 3) ^ ((row >> 1) & 3);
                gld16(w2b + (size_t)row * 1024 + s * 128 + kt2 * 32 + sl * 8,
                      &SB[(i * 256 + wbase) * 8]);
            }
            __syncthreads();
            bfrag af[2], bw[4];
            #pragma unroll
            for (int fm = 0; fm < 2; ++fm) {
                const int r = fm * 16 + fr;
                af[fm] = *(const bfrag*)&HS[r * 128 + (((kt2 * 4 + kg) ^ (r & 7)) * 8)];
            }
            #pragma unroll
            for (int fn = 0; fn < 4; ++fn) {
                const int r = wn * 64 + fn * 16 + fr;
                bw[fn] = *(const bfrag*)&SB[r * 32 + ((kg ^ ((r >> 1) & 3)) * 8)];
            }
            #pragma unroll
            for (int fm = 0; fm < 2; ++fm)
                #pragma unroll
                for (int fn = 0; fn < 4; ++fn)
                    acc[fm][fn] = __builtin_amdgcn_mfma_f32_16x16x32_bf16(
                        af[fm], bw[fn], acc[fm][fn], 0, 0, 0);
        }
        __syncthreads();                         // SB/HS readers done
    }

    // ---- epilogue: out = x1 + acc + b2
    #pragma unroll
    for (int fn = 0; fn < 4; ++fn) {
        const int col = wn * 64 + fn * 16 + fr;
        const float bv = b2[col];
        #pragma unroll
        for (int fm = 0; fm < 2; ++fm) {
            #pragma unroll
            for (int r = 0; r < 4; ++r) {
                const int mi = fm * 16 + kg * 4 + r;
                const size_t gi = (size_t)(grow0 + mi) * CDIM + col;
                io[gi] += acc[fm][fn][r] + bv;
            }
        }
    }
}

// ---------------------------------------------------------------------------
extern "C" void kernel_launch(void* const* d_in, const int* in_sizes, int n_in,
                              void* d_out, int out_size, void* d_ws, size_t ws_size,
                              hipStream_t stream)
{
    const float* x     = (const float*)d_in[0];
    const float* g1    = (const float*)d_in[1];
    const float* beta1 = (const float*)d_in[2];
    const float* wqkv  = (const float*)d_in[3];
    const float* bqkv  = (const float*)d_in[4];
    const float* btab  = (const float*)d_in[5];
    const float* wproj = (const float*)d_in[6];
    const float* bproj = (const float*)d_in[7];
    const float* g2    = (const float*)d_in[8];
    const float* beta2 = (const float*)d_in[9];
    const float* w1    = (const float*)d_in[10];
    const float* b1    = (const float*)d_in[11];
    const float* w2    = (const float*)d_in[12];
    const float* b2    = (const float*)d_in[13];
    const int*   wti   = (const int*)d_in[17];
    float* out = (float*)d_out;

    const size_t COMB_ELEMS = (size_t)8 * 8 * 81 * 256;                // 1327104
    const size_t WQKV_E = (size_t)C3 * CDIM, WP_E = (size_t)CDIM * CDIM;
    const size_t W1_E = (size_t)HID * CDIM,  W2_E = (size_t)CDIM * HID;
    const size_t base_bytes = COMB_ELEMS * 4
                            + (WQKV_E + WP_E + W1_E + W2_E) * 2;

    int nch = 32;
    for (int cand : {4, 8, 16, 32}) {
        const size_t rows = (size_t)L_TOK / cand;
        if (base_bytes + rows * (C3 + CDIM) * 2 <= ws_size) { nch = cand; break; }
    }
    const int wins_per = NWIN / nch;
    const int rows_per = wins_per * NTOK;

    char* wsp = (char*)d_ws;
    float* comb = (float*)wsp;   wsp += COMB_ELEMS * 4;
    ushort* wall = (ushort*)wsp; wsp += (WQKV_E + WP_E + W1_E + W2_E) * 2;
    ushort* wq_b = wall;
    ushort* wp_b = wall + WQKV_E;
    ushort* w1_b = wall + WQKV_E + WP_E;
    ushort* w2_b = wall + WQKV_E + WP_E + W1_E;
    ushort* ratt = (ushort*)wsp; wsp += (size_t)rows_per * CDIM * 2;  // xw/attn-out (shared)
    ushort* rbig = (ushort*)wsp;                 // rows_per * C3 bf16

    cvt4_kernel<<<768, 256, 0, stream>>>(wqkv, wproj, w1, w2, wall);
    comb_pre_kernel<<<(int)(COMB_ELEMS / 256), 256, 0, stream>>>(btab, wti, comb);

    // Phase 1: LN1+shift (bf16, once) -> QKV -> attention -> proj(+reverse+roll+residual)
    for (int c = 0; c < nch; ++c) {
        const int row0 = c * rows_per;
        const int win0 = c * wins_per;
        ln1_kernel<<<rows_per / 4, 256, 0, stream>>>(x, g1, beta1, ratt, row0);
        mgemm<0><<<dim3(C3 / 128, rows_per / 128), 256, 0, stream>>>(
            ratt, wq_b, bqkv, rbig, nullptr, CDIM, row0);
        attn_kernel<<<wins_per * NHEADS, 64, 0, stream>>>(rbig, comb, ratt, win0);
        mgemm<1><<<dim3(CDIM / 128, rows_per / 128), 256, 0, stream>>>(
            ratt, wp_b, bproj, out, x, CDIM, row0);
    }

    // Phase 2: fused LN2 + MLP1 + GELU + MLP2 + residual (hidden stays on-chip)
    mlp_fused<<<L_TOK / 32, 256, 0, stream>>>(out, w1_b, b1, w2_b, b2, g2, beta2);
}